// Round 1
// baseline (538.896 us; speedup 1.0000x reference)
//
#include <hip/hip_runtime.h>
#include <math.h>

typedef unsigned short u16;
typedef unsigned int   u32;
using f32x4  = __attribute__((ext_vector_type(4))) float;
using bf16x8 = __attribute__((ext_vector_type(8))) __bf16;

#define HIDDEN   2880
#define QKVD     5120
#define QD       4096
#define TTOK     2048
#define NKV      8
#define QMULT    8
#define HD       64
#define NPAD     2944   // w_out rows padded to 23*128

static __device__ __forceinline__ float bflo(u32 u){ return __uint_as_float(u << 16); }
static __device__ __forceinline__ float bfhi(u32 u){ return __uint_as_float(u & 0xffff0000u); }
static __device__ __forceinline__ u16 f2bf(float f){
    u32 u = __float_as_uint(f);
    u32 r = (u + 0x7fffu + ((u >> 16) & 1u)) >> 16;
    return (u16)r;
}

static __device__ __forceinline__ void glds16(const void* g, void* l) {
    __builtin_amdgcn_global_load_lds(
        (__attribute__((address_space(1))) void*)g,
        (__attribute__((address_space(3))) void*)l,
        16, 0, 0);
}

// ---------------- weight conversion ----------------
__global__ __launch_bounds__(256) void cvt_bf16_kernel(const float* __restrict__ src,
                                                       u16* __restrict__ dst, int n4) {
    int i = blockIdx.x * 256 + threadIdx.x;
    if (i >= n4) return;
    float4 f = ((const float4*)src)[i];
    ushort4 o;
    o.x = f2bf(f.x); o.y = f2bf(f.y); o.z = f2bf(f.z); o.w = f2bf(f.w);
    ((ushort4*)dst)[i] = o;
}

// w_out [2880][4096] f32 -> [2944][4096] bf16, rows >=2880 zeroed
__global__ __launch_bounds__(256) void cvt_wout_kernel(const float* __restrict__ src,
                                                       u16* __restrict__ dst) {
    int i = blockIdx.x * 256 + threadIdx.x;       // over NPAD*QD/4
    int idx = i * 4;
    int row = idx >> 12;        // /4096
    int col = idx & 4095;
    ushort4 o;
    if (row < HIDDEN) {
        float4 f = *(const float4*)(src + (long)row * QD + col);
        o.x = f2bf(f.x); o.y = f2bf(f.y); o.z = f2bf(f.z); o.w = f2bf(f.w);
    } else {
        o.x = 0; o.y = 0; o.z = 0; o.w = 0;
    }
    ((ushort4*)dst)[i] = o;
}

// ---------------- RMSNorm ----------------
__global__ __launch_bounds__(256) void rmsnorm_kernel(const float* __restrict__ x,
                                                      const float* __restrict__ scale,
                                                      u16* __restrict__ h) {
    const int t = blockIdx.x;
    const int tid = threadIdx.x;
    const float4* xr = (const float4*)(x + (long)t * HIDDEN);
    float4 v[3];
    float ss = 0.f;
    #pragma unroll
    for (int it = 0; it < 3; ++it) {
        int i4 = tid + it * 256;
        if (i4 < 720) {
            v[it] = xr[i4];
            ss += v[it].x*v[it].x + v[it].y*v[it].y + v[it].z*v[it].z + v[it].w*v[it].w;
        }
    }
    #pragma unroll
    for (int off = 32; off > 0; off >>= 1) ss += __shfl_down(ss, off);
    __shared__ float red[4];
    if ((tid & 63) == 0) red[tid >> 6] = ss;
    __syncthreads();
    float tot = red[0] + red[1] + red[2] + red[3];
    float rr = rsqrtf(tot * (1.0f / HIDDEN) + 1e-5f);
    ushort4* hr = (ushort4*)(h + (long)t * HIDDEN);
    #pragma unroll
    for (int it = 0; it < 3; ++it) {
        int i4 = tid + it * 256;
        if (i4 < 720) {
            float4 s4 = ((const float4*)scale)[i4];
            ushort4 o;
            o.x = f2bf(v[it].x * rr * s4.x);
            o.y = f2bf(v[it].y * rr * s4.y);
            o.z = f2bf(v[it].z * rr * s4.z);
            o.w = f2bf(v[it].w * rr * s4.w);
            hr[i4] = o;
        }
    }
}

// ---------------- GEMM: C[M,N] = A[M,K] @ B[N,K]^T + bias (+resid) ----------------
// m97 structure: 128x128 tile, BK=32, 4 waves (2x2), 16x16x32 bf16 MFMA,
// global_load_lds width=16 staging (LDS dest = uniform base + lane*16).
template<bool OUT_BF16, bool RES>
__global__ __launch_bounds__(256) void gemm_bt(const u16* __restrict__ A,
                                               const u16* __restrict__ B,
                                               const float* __restrict__ bias,
                                               const float* __restrict__ resid,
                                               void* __restrict__ C,
                                               int M, int N, int K, int ldc) {
    __shared__ u16 lsA[128 * 32];
    __shared__ u16 lsB[128 * 32];
    const int tid  = threadIdx.x;
    const int lane = tid & 63;
    const int wv   = tid >> 6;          // wave 0..3
    const int wm   = wv >> 1, wn = wv & 1;
    const long m0 = (long)blockIdx.y * 128;
    const long n0 = (long)blockIdx.x * 128;
    const int sr = lane >> 2;           // staging row 0..15
    const int sc = lane & 3;            // staging 16B chunk 0..3

    f32x4 acc[4][4];
    #pragma unroll
    for (int i = 0; i < 4; ++i)
        #pragma unroll
        for (int j = 0; j < 4; ++j) acc[i][j] = f32x4{0.f, 0.f, 0.f, 0.f};

    const int fr = lane & 15;           // fragment row
    const int fk = (lane >> 4) * 8;     // fragment k offset

    const u16* Abase = A + (m0 + wv * 32 + sr) * (long)K + sc * 8;
    const u16* Bbase = B + (n0 + wv * 32 + sr) * (long)K + sc * 8;
    u16* lA0 = &lsA[(wv * 32) * 32];
    u16* lA1 = &lsA[(wv * 32 + 16) * 32];
    u16* lB0 = &lsB[(wv * 32) * 32];
    u16* lB1 = &lsB[(wv * 32 + 16) * 32];
    const long rowK16 = 16 * (long)K;

    for (int k0 = 0; k0 < K; k0 += 32) {
        glds16(Abase + k0,          lA0);
        glds16(Abase + k0 + rowK16, lA1);
        glds16(Bbase + k0,          lB0);
        glds16(Bbase + k0 + rowK16, lB1);
        __syncthreads();
        bf16x8 af[4], bfg[4];
        #pragma unroll
        for (int mi = 0; mi < 4; ++mi)
            af[mi] = *(const bf16x8*)&lsA[(wm * 64 + mi * 16 + fr) * 32 + fk];
        #pragma unroll
        for (int ni = 0; ni < 4; ++ni)
            bfg[ni] = *(const bf16x8*)&lsB[(wn * 64 + ni * 16 + fr) * 32 + fk];
        #pragma unroll
        for (int mi = 0; mi < 4; ++mi)
            #pragma unroll
            for (int ni = 0; ni < 4; ++ni)
                acc[mi][ni] = __builtin_amdgcn_mfma_f32_16x16x32_bf16(af[mi], bfg[ni], acc[mi][ni], 0, 0, 0);
        __syncthreads();
    }

    // epilogue: C/D layout col=lane&15, row=(lane>>4)*4+reg  [m89-verified]
    const int cr = (lane >> 4) * 4;
    const int cc = lane & 15;
    #pragma unroll
    for (int ni = 0; ni < 4; ++ni) {
        long col = n0 + wn * 64 + ni * 16 + cc;
        if (col < N) {
            float bv = bias[col];
            #pragma unroll
            for (int mi = 0; mi < 4; ++mi) {
                #pragma unroll
                for (int r2 = 0; r2 < 4; ++r2) {
                    long row = m0 + wm * 64 + mi * 16 + cr + r2;
                    float vvv = acc[mi][ni][r2] + bv;
                    if (RES) vvv += resid[row * (long)N + col];
                    if (OUT_BF16) ((u16*)C)[row * (long)ldc + col] = f2bf(vvv);
                    else          ((float*)C)[row * (long)ldc + col] = vvv;
                }
            }
        }
    }
}

// ---------------- RoPE (YaRN) ----------------
__global__ __launch_bounds__(256) void rope_kernel(const u16* __restrict__ qkv,
                                                   u16* __restrict__ qr,
                                                   u16* __restrict__ kr,
                                                   u16* __restrict__ vr) {
    const int t = blockIdx.x;
    const int tid = threadIdx.x;
    __shared__ float cs[32], sn[32];
    if (tid < 32) {
        float fi = (float)tid;
        float freq   = exp2f(17.1946032f * (fi * (1.0f / 32.0f)));   // 150000^(i/32)
        float interp = 1.0f / (32.0f * freq);
        float extra  = 1.0f / freq;
        float ramp   = (fi - 8.0927802f) * (1.0f / (17.3980220f - 8.0927802f));
        float rc     = fminf(fmaxf(ramp, 0.0f), 1.0f);               // = 1 - mask
        float invf   = interp * rc + extra * (1.0f - rc);
        float ang    = (float)t * invf;
        cs[tid] = cosf(ang) * 1.3465736f;                            // * concentration
        sn[tid] = sinf(ang) * 1.3465736f;
    }
    __syncthreads();
    const u16* row = qkv + (long)t * QKVD;
    // Q: 64 heads x 32 pairs
    for (int p = tid; p < 2048; p += 256) {
        int hd2 = p >> 5, i = p & 31;
        u32 pr = *(const u32*)(row + hd2 * 64 + 2 * i);
        float a = bflo(pr), b = bfhi(pr);
        float o1 = a * cs[i] - b * sn[i];
        float o2 = b * cs[i] + a * sn[i];
        *(u32*)(qr + (long)t * QD + hd2 * 64 + 2 * i) = (u32)f2bf(o1) | ((u32)f2bf(o2) << 16);
    }
    // K: 8 heads x 32 pairs == 256 threads; head-major layout [kv][t][64]
    {
        int kv = tid >> 5, i = tid & 31;
        u32 pr = *(const u32*)(row + QD + kv * 64 + 2 * i);
        float a = bflo(pr), b = bfhi(pr);
        float o1 = a * cs[i] - b * sn[i];
        float o2 = b * cs[i] + a * sn[i];
        *(u32*)(kr + ((long)kv * TTOK + t) * HD + 2 * i) = (u32)f2bf(o1) | ((u32)f2bf(o2) << 16);
    }
    // V copy: 8 heads x 64 = 256 u32; head-major [kv][t][64]
    {
        int kv = tid >> 5, d2 = tid & 31;
        u32 pr = *(const u32*)(row + QD + 512 + kv * 64 + 2 * d2);
        *(u32*)(vr + ((long)kv * TTOK + t) * HD + 2 * d2) = pr;
    }
}

// ---------------- sliding-window attention with sink ----------------
// block = (32 tokens) x (1 kv head); 256 threads = 8 qheads x 32 tokens.
// K/V window of 160 keys staged in LDS (stride 72 = 16B-aligned pad).
// Scores bounded (|s| <= ||q||*||k||/8 ~ 8) -> fixed-max softmax (m=0) is safe.
__global__ __launch_bounds__(256, 2) void attn_kernel(const u16* __restrict__ qr,
                                                      const u16* __restrict__ kr,
                                                      const u16* __restrict__ vr,
                                                      const float* __restrict__ sinks,
                                                      u16* __restrict__ o) {
    const int t0 = blockIdx.x * 32;
    const int h  = blockIdx.y;
    const int tid = threadIdx.x;
    __shared__ __align__(16) u16 ks[160][72];
    __shared__ __align__(16) u16 vs[160][72];
    const u16* kb = kr + (long)h * TTOK * HD;
    const u16* vb = vr + (long)h * TTOK * HD;
    for (int idx = tid; idx < 160 * 8; idx += 256) {
        int rr = idx >> 3, cc = idx & 7;
        int tk = t0 - 128 + rr;
        int tks = tk < 0 ? 0 : tk;      // clamped; masked keys never read
        *(uint4*)&ks[rr][cc * 8] = *(const uint4*)(kb + (long)tks * HD + cc * 8);
        *(uint4*)&vs[rr][cc * 8] = *(const uint4*)(vb + (long)tks * HD + cc * 8);
    }
    __syncthreads();
    const int qh = tid >> 5, tl = tid & 31;
    const int t = t0 + tl;
    const int head = h * QMULT + qh;

    float2 q2[32];
    {
        const uint4* qp = (const uint4*)(qr + (long)t * QD + head * HD);
        #pragma unroll
        for (int c4 = 0; c4 < 8; ++c4) {
            uint4 u = qp[c4];
            q2[c4*4+0] = make_float2(bflo(u.x), bfhi(u.x));
            q2[c4*4+1] = make_float2(bflo(u.y), bfhi(u.y));
            q2[c4*4+2] = make_float2(bflo(u.z), bfhi(u.z));
            q2[c4*4+3] = make_float2(bflo(u.w), bfhi(u.w));
        }
    }
    float2 acc2[32];
    #pragma unroll
    for (int j = 0; j < 32; ++j) acc2[j] = make_float2(0.f, 0.f);

    float l = __expf(sinks[head] * 0.69314718f);   // sink logit, m=0 reference
    const int w0 = (t >= 128) ? 0 : (128 - t);
    for (int w = w0; w <= 128; ++w) {
        const int rr = tl + w;
        const uint4* krow = (const uint4*)&ks[rr][0];
        float2 s2 = make_float2(0.f, 0.f);
        #pragma unroll
        for (int c4 = 0; c4 < 8; ++c4) {
            uint4 u = krow[c4];
            s2.x += q2[c4*4+0].x * bflo(u.x);  s2.y += q2[c4*4+0].y * bfhi(u.x);
            s2.x += q2[c4*4+1].x * bflo(u.y);  s2.y += q2[c4*4+1].y * bfhi(u.y);
            s2.x += q2[c4*4+2].x * bflo(u.z);  s2.y += q2[c4*4+2].y * bfhi(u.z);
            s2.x += q2[c4*4+3].x * bflo(u.w);  s2.y += q2[c4*4+3].y * bfhi(u.w);
        }
        float p = __expf((s2.x + s2.y) * 0.125f);
        l += p;
        const uint4* vrow = (const uint4*)&vs[rr][0];
        #pragma unroll
        for (int c4 = 0; c4 < 8; ++c4) {
            uint4 u = vrow[c4];
            acc2[c4*4+0].x += p * bflo(u.x);  acc2[c4*4+0].y += p * bfhi(u.x);
            acc2[c4*4+1].x += p * bflo(u.y);  acc2[c4*4+1].y += p * bfhi(u.y);
            acc2[c4*4+2].x += p * bflo(u.z);  acc2[c4*4+2].y += p * bfhi(u.z);
            acc2[c4*4+3].x += p * bflo(u.w);  acc2[c4*4+3].y += p * bfhi(u.w);
        }
    }
    float inv = 1.0f / l;
    u32* op = (u32*)(o + (long)t * QD + head * HD);
    #pragma unroll
    for (int j = 0; j < 32; ++j)
        op[j] = (u32)f2bf(acc2[j].x * inv) | ((u32)f2bf(acc2[j].y * inv) << 16);
}

// ---------------- launcher ----------------
extern "C" void kernel_launch(void* const* d_in, const int* in_sizes, int n_in,
                              void* d_out, int out_size, void* d_ws, size_t ws_size,
                              hipStream_t stream) {
    const float* x      = (const float*)d_in[0];
    const float* nscale = (const float*)d_in[1];
    const float* w_qkv  = (const float*)d_in[2];
    const float* b_qkv  = (const float*)d_in[3];
    const float* sinks  = (const float*)d_in[4];
    const float* w_out  = (const float*)d_in[5];
    const float* b_out  = (const float*)d_in[6];
    float* out = (float*)d_out;

    char* ws = (char*)d_ws;
    size_t off = 0;
    auto alloc = [&](size_t bytes) { void* p = ws + off; off += (bytes + 255) & ~(size_t)255; return p; };
    u16* wqkv_bf = (u16*)alloc((size_t)QKVD * HIDDEN * 2);   // 29.5 MB
    u16* wout_bf = (u16*)alloc((size_t)NPAD * QD * 2);       // 24.1 MB
    u16* h       = (u16*)alloc((size_t)TTOK * HIDDEN * 2);   // 11.8 MB
    u16* qkv     = (u16*)alloc((size_t)TTOK * QKVD * 2);     // 21.0 MB
    u16* qrot    = (u16*)alloc((size_t)TTOK * QD * 2);       // 16.8 MB
    u16* krot    = (u16*)alloc((size_t)NKV * TTOK * HD * 2); // 2.1 MB
    u16* vrot    = (u16*)alloc((size_t)NKV * TTOK * HD * 2); // 2.1 MB
    u16* attn    = qkv;  // qkv dead after rope; reuse as attention output [2048][4096]

    cvt_bf16_kernel<<<(QKVD * HIDDEN / 4 + 255) / 256, 256, 0, stream>>>(w_qkv, wqkv_bf, QKVD * HIDDEN / 4);
    cvt_wout_kernel<<<(NPAD * QD / 4) / 256, 256, 0, stream>>>(w_out, wout_bf);
    rmsnorm_kernel<<<TTOK, 256, 0, stream>>>(x, nscale, h);
    gemm_bt<true, false><<<dim3(QKVD / 128, TTOK / 128), 256, 0, stream>>>(
        h, wqkv_bf, b_qkv, nullptr, qkv, TTOK, QKVD, HIDDEN, QKVD);
    rope_kernel<<<TTOK, 256, 0, stream>>>(qkv, qrot, krot, vrot);
    attn_kernel<<<dim3(TTOK / 32, NKV), 256, 0, stream>>>(qrot, krot, vrot, sinks, attn);
    gemm_bt<false, true><<<dim3(NPAD / 128, TTOK / 128), 256, 0, stream>>>(
        attn, wout_bf, b_out, x, out, TTOK, HIDDEN, QD, HIDDEN);
}

// Round 2
// 439.860 us; speedup vs baseline: 1.2252x; 1.2252x over previous
//
#include <hip/hip_runtime.h>
#include <math.h>

typedef unsigned short u16;
typedef unsigned int   u32;
using f32x4  = __attribute__((ext_vector_type(4))) float;
using bf16x8 = __attribute__((ext_vector_type(8))) __bf16;

#define HIDDEN   2880
#define QKVD     5120
#define QD       4096
#define TTOK     2048
#define NKV      8
#define QMULT    8
#define HD       64
#define NPAD     2944   // w_out rows padded to 23*128

static __device__ __forceinline__ float bflo(u32 u){ return __uint_as_float(u << 16); }
static __device__ __forceinline__ float bfhi(u32 u){ return __uint_as_float(u & 0xffff0000u); }
static __device__ __forceinline__ u16 f2bf(float f){
    u32 u = __float_as_uint(f);
    u32 r = (u + 0x7fffu + ((u >> 16) & 1u)) >> 16;
    return (u16)r;
}

static __device__ __forceinline__ void glds16(const void* g, void* l) {
    __builtin_amdgcn_global_load_lds(
        (__attribute__((address_space(1))) void*)g,
        (__attribute__((address_space(3))) void*)l,
        16, 0, 0);
}

// ---------------- weight conversion ----------------
__global__ __launch_bounds__(256) void cvt_bf16_kernel(const float* __restrict__ src,
                                                       u16* __restrict__ dst, int n4) {
    int i = blockIdx.x * 256 + threadIdx.x;
    if (i >= n4) return;
    float4 f = ((const float4*)src)[i];
    ushort4 o;
    o.x = f2bf(f.x); o.y = f2bf(f.y); o.z = f2bf(f.z); o.w = f2bf(f.w);
    ((ushort4*)dst)[i] = o;
}

// w_out [2880][4096] f32 -> [2944][4096] bf16, rows >=2880 zeroed
__global__ __launch_bounds__(256) void cvt_wout_kernel(const float* __restrict__ src,
                                                       u16* __restrict__ dst) {
    int i = blockIdx.x * 256 + threadIdx.x;       // over NPAD*QD/4
    int idx = i * 4;
    int row = idx >> 12;        // /4096
    int col = idx & 4095;
    ushort4 o;
    if (row < HIDDEN) {
        float4 f = *(const float4*)(src + (long)row * QD + col);
        o.x = f2bf(f.x); o.y = f2bf(f.y); o.z = f2bf(f.z); o.w = f2bf(f.w);
    } else {
        o.x = 0; o.y = 0; o.z = 0; o.w = 0;
    }
    ((ushort4*)dst)[i] = o;
}

// ---------------- RMSNorm ----------------
__global__ __launch_bounds__(256) void rmsnorm_kernel(const float* __restrict__ x,
                                                      const float* __restrict__ scale,
                                                      u16* __restrict__ h) {
    const int t = blockIdx.x;
    const int tid = threadIdx.x;
    const float4* xr = (const float4*)(x + (long)t * HIDDEN);
    float4 v[3];
    float ss = 0.f;
    #pragma unroll
    for (int it = 0; it < 3; ++it) {
        int i4 = tid + it * 256;
        if (i4 < 720) {
            v[it] = xr[i4];
            ss += v[it].x*v[it].x + v[it].y*v[it].y + v[it].z*v[it].z + v[it].w*v[it].w;
        }
    }
    #pragma unroll
    for (int off = 32; off > 0; off >>= 1) ss += __shfl_down(ss, off);
    __shared__ float red[4];
    if ((tid & 63) == 0) red[tid >> 6] = ss;
    __syncthreads();
    float tot = red[0] + red[1] + red[2] + red[3];
    float rr = rsqrtf(tot * (1.0f / HIDDEN) + 1e-5f);
    ushort4* hr = (ushort4*)(h + (long)t * HIDDEN);
    #pragma unroll
    for (int it = 0; it < 3; ++it) {
        int i4 = tid + it * 256;
        if (i4 < 720) {
            float4 s4 = ((const float4*)scale)[i4];
            ushort4 o;
            o.x = f2bf(v[it].x * rr * s4.x);
            o.y = f2bf(v[it].y * rr * s4.y);
            o.z = f2bf(v[it].z * rr * s4.z);
            o.w = f2bf(v[it].w * rr * s4.w);
            hr[i4] = o;
        }
    }
}

// ---------------- GEMM: C[M,N] = A[M,K] @ B[N,K]^T + bias (+resid) ----------------
template<bool OUT_BF16, bool RES>
__global__ __launch_bounds__(256) void gemm_bt(const u16* __restrict__ A,
                                               const u16* __restrict__ B,
                                               const float* __restrict__ bias,
                                               const float* __restrict__ resid,
                                               void* __restrict__ C,
                                               int M, int N, int K, int ldc) {
    __shared__ u16 lsA[128 * 32];
    __shared__ u16 lsB[128 * 32];
    const int tid  = threadIdx.x;
    const int lane = tid & 63;
    const int wv   = tid >> 6;          // wave 0..3
    const int wm   = wv >> 1, wn = wv & 1;
    const long m0 = (long)blockIdx.y * 128;
    const long n0 = (long)blockIdx.x * 128;
    const int sr = lane >> 2;           // staging row 0..15
    const int sc = lane & 3;            // staging 16B chunk 0..3

    f32x4 acc[4][4];
    #pragma unroll
    for (int i = 0; i < 4; ++i)
        #pragma unroll
        for (int j = 0; j < 4; ++j) acc[i][j] = f32x4{0.f, 0.f, 0.f, 0.f};

    const int fr = lane & 15;           // fragment row
    const int fk = (lane >> 4) * 8;     // fragment k offset

    const u16* Abase = A + (m0 + wv * 32 + sr) * (long)K + sc * 8;
    const u16* Bbase = B + (n0 + wv * 32 + sr) * (long)K + sc * 8;
    u16* lA0 = &lsA[(wv * 32) * 32];
    u16* lA1 = &lsA[(wv * 32 + 16) * 32];
    u16* lB0 = &lsB[(wv * 32) * 32];
    u16* lB1 = &lsB[(wv * 32 + 16) * 32];
    const long rowK16 = 16 * (long)K;

    for (int k0 = 0; k0 < K; k0 += 32) {
        glds16(Abase + k0,          lA0);
        glds16(Abase + k0 + rowK16, lA1);
        glds16(Bbase + k0,          lB0);
        glds16(Bbase + k0 + rowK16, lB1);
        __syncthreads();
        bf16x8 af[4], bfg[4];
        #pragma unroll
        for (int mi = 0; mi < 4; ++mi)
            af[mi] = *(const bf16x8*)&lsA[(wm * 64 + mi * 16 + fr) * 32 + fk];
        #pragma unroll
        for (int ni = 0; ni < 4; ++ni)
            bfg[ni] = *(const bf16x8*)&lsB[(wn * 64 + ni * 16 + fr) * 32 + fk];
        #pragma unroll
        for (int mi = 0; mi < 4; ++mi)
            #pragma unroll
            for (int ni = 0; ni < 4; ++ni)
                acc[mi][ni] = __builtin_amdgcn_mfma_f32_16x16x32_bf16(af[mi], bfg[ni], acc[mi][ni], 0, 0, 0);
        __syncthreads();
    }

    // epilogue: C/D layout col=lane&15, row=(lane>>4)*4+reg  [m89-verified]
    const int cr = (lane >> 4) * 4;
    const int cc = lane & 15;
    #pragma unroll
    for (int ni = 0; ni < 4; ++ni) {
        long col = n0 + wn * 64 + ni * 16 + cc;
        if (col < N) {
            float bv = bias[col];
            #pragma unroll
            for (int mi = 0; mi < 4; ++mi) {
                #pragma unroll
                for (int r2 = 0; r2 < 4; ++r2) {
                    long row = m0 + wm * 64 + mi * 16 + cr + r2;
                    float vvv = acc[mi][ni][r2] + bv;
                    if (RES) vvv += resid[row * (long)N + col];
                    if (OUT_BF16) ((u16*)C)[row * (long)ldc + col] = f2bf(vvv);
                    else          ((float*)C)[row * (long)ldc + col] = vvv;
                }
            }
        }
    }
}

// ---------------- RoPE (YaRN) ----------------
__global__ __launch_bounds__(256) void rope_kernel(const u16* __restrict__ qkv,
                                                   u16* __restrict__ qr,
                                                   u16* __restrict__ kr,
                                                   u16* __restrict__ vr) {
    const int t = blockIdx.x;
    const int tid = threadIdx.x;
    __shared__ float cs[32], sn[32];
    if (tid < 32) {
        float fi = (float)tid;
        float freq   = exp2f(17.1946032f * (fi * (1.0f / 32.0f)));   // 150000^(i/32)
        float interp = 1.0f / (32.0f * freq);
        float extra  = 1.0f / freq;
        float ramp   = (fi - 8.0927802f) * (1.0f / (17.3980220f - 8.0927802f));
        float rc     = fminf(fmaxf(ramp, 0.0f), 1.0f);               // = 1 - mask
        float invf   = interp * rc + extra * (1.0f - rc);
        float ang    = (float)t * invf;
        cs[tid] = cosf(ang) * 1.3465736f;                            // * concentration
        sn[tid] = sinf(ang) * 1.3465736f;
    }
    __syncthreads();
    const u16* row = qkv + (long)t * QKVD;
    // Q: 64 heads x 32 pairs
    for (int p = tid; p < 2048; p += 256) {
        int hd2 = p >> 5, i = p & 31;
        u32 pr = *(const u32*)(row + hd2 * 64 + 2 * i);
        float a = bflo(pr), b = bfhi(pr);
        float o1 = a * cs[i] - b * sn[i];
        float o2 = b * cs[i] + a * sn[i];
        *(u32*)(qr + (long)t * QD + hd2 * 64 + 2 * i) = (u32)f2bf(o1) | ((u32)f2bf(o2) << 16);
    }
    // K: 8 heads x 32 pairs == 256 threads; head-major layout [kv][t][64]
    {
        int kv = tid >> 5, i = tid & 31;
        u32 pr = *(const u32*)(row + QD + kv * 64 + 2 * i);
        float a = bflo(pr), b = bfhi(pr);
        float o1 = a * cs[i] - b * sn[i];
        float o2 = b * cs[i] + a * sn[i];
        *(u32*)(kr + ((long)kv * TTOK + t) * HD + 2 * i) = (u32)f2bf(o1) | ((u32)f2bf(o2) << 16);
    }
    // V copy: 8 heads x 64 = 256 u32; head-major [kv][t][64]
    {
        int kv = tid >> 5, d2 = tid & 31;
        u32 pr = *(const u32*)(row + QD + 512 + kv * 64 + 2 * d2);
        *(u32*)(vr + ((long)kv * TTOK + t) * HD + 2 * d2) = pr;
    }
}

// ---------------- MFMA sliding-window attention with sink ----------------
// block = 16 tokens x 1 kv-head x 4 q-heads (blockIdx.z picks q-head group).
// wave w handles q-head qhg*4+w: 1 M-tile (16 tokens) x 9 N-tiles (144 keys).
// QK^T and PV via mfma_f32_16x16x32_bf16; P round-trips LDS C->A layout;
// V stored transposed [d][key] for B-operand contiguity. Fixed-max softmax
// (scores bounded), sink = 2^sink enters denominator only.
__global__ __launch_bounds__(256, 2) void attn_kernel(const u16* __restrict__ qr,
                                                      const u16* __restrict__ kr,
                                                      const u16* __restrict__ vr,
                                                      const float* __restrict__ sinks,
                                                      u16* __restrict__ o) {
    const int t0  = blockIdx.x * 16;
    const int h   = blockIdx.y;
    const int qhg = blockIdx.z;
    const int tid = threadIdx.x;
    const int lane = tid & 63, wv = tid >> 6;
    __shared__ __align__(16) u16 ks[144][72];    // K rows [key][64+pad]
    __shared__ __align__(16) u16 Vt[64][168];    // V^T [d][key], cols 144..159 zero
    __shared__ __align__(16) u16 P [4][16][168]; // per-wave P [token][key], cols 144..159 zero
    const u16* kb = kr + (long)h * TTOK * HD;
    const u16* vb = vr + (long)h * TTOK * HD;

    // stage K rows (coalesced)
    #pragma unroll
    for (int i = 0; i < 5; ++i) {
        int idx = i * 256 + tid;
        if (idx < 144 * 8) {
            int rr = idx >> 3, c = idx & 7;
            int tk = t0 - 128 + rr;
            int tks = tk < 0 ? 0 : tk;          // clamped; masked later
            *(uint4*)&ks[rr][c * 8] = *(const uint4*)(kb + (long)tks * HD + c * 8);
        }
    }
    // stage V transposed: thread -> one key, 8 dims per pass
    #pragma unroll
    for (int c4 = 0; c4 < 8; ++c4) {
        if (tid < 144) {
            int tk = t0 - 128 + tid;
            int tks = tk < 0 ? 0 : tk;
            uint4 v4 = *(const uint4*)(vb + (long)tks * HD + c4 * 8);
            int d0 = c4 * 8;
            Vt[d0+0][tid] = (u16)(v4.x & 0xffff); Vt[d0+1][tid] = (u16)(v4.x >> 16);
            Vt[d0+2][tid] = (u16)(v4.y & 0xffff); Vt[d0+3][tid] = (u16)(v4.y >> 16);
            Vt[d0+4][tid] = (u16)(v4.z & 0xffff); Vt[d0+5][tid] = (u16)(v4.z >> 16);
            Vt[d0+6][tid] = (u16)(v4.w & 0xffff); Vt[d0+7][tid] = (u16)(v4.w >> 16);
        }
    }
    // zero-fill Vt cols 144..159 (read by last PV K-step; P there is zero but must be finite)
    if (tid < 128) {
        *(uint4*)&Vt[tid >> 1][144 + (tid & 1) * 8] = uint4{0, 0, 0, 0};
    }
    // zero-fill P cols 144..159 (per wave)
    if (lane < 32) {
        *(uint4*)&P[wv][lane >> 1][144 + (lane & 1) * 8] = uint4{0, 0, 0, 0};
    }
    __syncthreads();

    const int qh   = qhg * 4 + wv;
    const int head = h * QMULT + qh;
    const int fr = lane & 15, fk = (lane >> 4) * 8;
    const int cr = (lane >> 4) * 4;

    // Q A-frags from global: A[m=token=fr][k = kstep*32 + fk + j]
    const u16* qrow = qr + (long)(t0 + fr) * QD + head * HD;
    bf16x8 qf0 = *(const bf16x8*)(qrow + fk);
    bf16x8 qf1 = *(const bf16x8*)(qrow + 32 + fk);

    const int kmin = 128 - t0;          // kk >= kmin <=> key token >= 0
    float lsum[4] = {0.f, 0.f, 0.f, 0.f};

    for (int nt = 0; nt < 9; ++nt) {
        bf16x8 b0 = *(const bf16x8*)&ks[nt * 16 + fr][fk];
        bf16x8 b1 = *(const bf16x8*)&ks[nt * 16 + fr][32 + fk];
        f32x4 s = f32x4{0.f, 0.f, 0.f, 0.f};
        s = __builtin_amdgcn_mfma_f32_16x16x32_bf16(qf0, b0, s, 0, 0, 0);
        s = __builtin_amdgcn_mfma_f32_16x16x32_bf16(qf1, b1, s, 0, 0, 0);
        const int kk = nt * 16 + fr;    // C-layout col = lane&15
        #pragma unroll
        for (int r = 0; r < 4; ++r) {
            int row = cr + r;           // token index within tile
            // valid window: kk in [max(row, kmin), row+128]
            bool valid = (kk >= row) && (kk <= row + 128) && (kk >= kmin);
            float p = valid ? __expf(s[r] * 0.125f) : 0.0f;
            lsum[r] += p;
            P[wv][row][kk] = f2bf(p);
        }
    }

    // PV: O[token][d] = sum_kk P[token][kk] * Vt[d][kk]
    f32x4 oacc[4];
    #pragma unroll
    for (int dt = 0; dt < 4; ++dt) oacc[dt] = f32x4{0.f, 0.f, 0.f, 0.f};
    #pragma unroll
    for (int k5 = 0; k5 < 5; ++k5) {
        const int k0 = k5 * 32;
        bf16x8 pa = *(const bf16x8*)&P[wv][fr][k0 + fk];
        #pragma unroll
        for (int dt = 0; dt < 4; ++dt) {
            bf16x8 vf = *(const bf16x8*)&Vt[dt * 16 + fr][k0 + fk];
            oacc[dt] = __builtin_amdgcn_mfma_f32_16x16x32_bf16(pa, vf, oacc[dt], 0, 0, 0);
        }
    }

    // denominator: reduce lsum over the 16 lanes holding the same rows, add sink
    #pragma unroll
    for (int r = 0; r < 4; ++r) {
        float v = lsum[r];
        v += __shfl_xor(v, 1);
        v += __shfl_xor(v, 2);
        v += __shfl_xor(v, 4);
        v += __shfl_xor(v, 8);
        lsum[r] = v;
    }
    const float sk = exp2f(sinks[head]);
    float inv[4];
    #pragma unroll
    for (int r = 0; r < 4; ++r) inv[r] = 1.0f / (lsum[r] + sk);

    // epilogue: C-layout row=(lane>>4)*4+r (token), col=lane&15 (d within dtile)
    #pragma unroll
    for (int dt = 0; dt < 4; ++dt) {
        #pragma unroll
        for (int r = 0; r < 4; ++r) {
            o[(long)(t0 + cr + r) * QD + head * HD + dt * 16 + fr] = f2bf(oacc[dt][r] * inv[r]);
        }
    }
}

// ---------------- launcher ----------------
extern "C" void kernel_launch(void* const* d_in, const int* in_sizes, int n_in,
                              void* d_out, int out_size, void* d_ws, size_t ws_size,
                              hipStream_t stream) {
    const float* x      = (const float*)d_in[0];
    const float* nscale = (const float*)d_in[1];
    const float* w_qkv  = (const float*)d_in[2];
    const float* b_qkv  = (const float*)d_in[3];
    const float* sinks  = (const float*)d_in[4];
    const float* w_out  = (const float*)d_in[5];
    const float* b_out  = (const float*)d_in[6];
    float* out = (float*)d_out;

    char* ws = (char*)d_ws;
    size_t off = 0;
    auto alloc = [&](size_t bytes) { void* p = ws + off; off += (bytes + 255) & ~(size_t)255; return p; };
    u16* wqkv_bf = (u16*)alloc((size_t)QKVD * HIDDEN * 2);   // 29.5 MB
    u16* wout_bf = (u16*)alloc((size_t)NPAD * QD * 2);       // 24.1 MB
    u16* h       = (u16*)alloc((size_t)TTOK * HIDDEN * 2);   // 11.8 MB
    u16* qkv     = (u16*)alloc((size_t)TTOK * QKVD * 2);     // 21.0 MB
    u16* qrot    = (u16*)alloc((size_t)TTOK * QD * 2);       // 16.8 MB
    u16* krot    = (u16*)alloc((size_t)NKV * TTOK * HD * 2); // 2.1 MB
    u16* vrot    = (u16*)alloc((size_t)NKV * TTOK * HD * 2); // 2.1 MB
    u16* attn    = qkv;  // qkv dead after rope; reuse as attention output [2048][4096]

    cvt_bf16_kernel<<<(QKVD * HIDDEN / 4 + 255) / 256, 256, 0, stream>>>(w_qkv, wqkv_bf, QKVD * HIDDEN / 4);
    cvt_wout_kernel<<<(NPAD * QD / 4) / 256, 256, 0, stream>>>(w_out, wout_bf);
    rmsnorm_kernel<<<TTOK, 256, 0, stream>>>(x, nscale, h);
    gemm_bt<true, false><<<dim3(QKVD / 128, TTOK / 128), 256, 0, stream>>>(
        h, wqkv_bf, b_qkv, nullptr, qkv, TTOK, QKVD, HIDDEN, QKVD);
    rope_kernel<<<TTOK, 256, 0, stream>>>(qkv, qrot, krot, vrot);
    attn_kernel<<<dim3(TTOK / 16, NKV, 2), 256, 0, stream>>>(qrot, krot, vrot, sinks, attn);
    gemm_bt<false, true><<<dim3(NPAD / 128, TTOK / 128), 256, 0, stream>>>(
        attn, wout_bf, b_out, x, out, TTOK, HIDDEN, QD, HIDDEN);
}

// Round 3
// 399.265 us; speedup vs baseline: 1.3497x; 1.1017x over previous
//
#include <hip/hip_runtime.h>
#include <math.h>

typedef unsigned short u16;
typedef unsigned int   u32;
using f32x4  = __attribute__((ext_vector_type(4))) float;
using bf16x8 = __attribute__((ext_vector_type(8))) __bf16;

#define HIDDEN   2880
#define QKVD     5120
#define QD       4096
#define TTOK     2048
#define NKV      8
#define QMULT    8
#define HD       64
#define NPAD     2944   // w_out rows padded to 23*128

// prep grid partition
#define PREP_QKV_BLOCKS  14400   // QKVD*HIDDEN/4/256
#define PREP_WOUT_BLOCKS 11776   // NPAD*QD/4/256
#define PREP_RMS_BLOCKS  2048

static __device__ __forceinline__ float bflo(u32 u){ return __uint_as_float(u << 16); }
static __device__ __forceinline__ float bfhi(u32 u){ return __uint_as_float(u & 0xffff0000u); }
static __device__ __forceinline__ u16 f2bf(float f){
    u32 u = __float_as_uint(f);
    u32 r = (u + 0x7fffu + ((u >> 16) & 1u)) >> 16;
    return (u16)r;
}

static __device__ __forceinline__ void glds16(const void* g, void* l) {
    __builtin_amdgcn_global_load_lds(
        (__attribute__((address_space(1))) void*)g,
        (__attribute__((address_space(3))) void*)l,
        16, 0, 0);
}

// ---------------- fused prep: w_qkv cvt | w_out cvt+pad | rmsnorm ----------------
__global__ __launch_bounds__(256) void prep_kernel(const float* __restrict__ w_qkv,
                                                   u16* __restrict__ wqkv_bf,
                                                   const float* __restrict__ w_out,
                                                   u16* __restrict__ wout_bf,
                                                   const float* __restrict__ x,
                                                   const float* __restrict__ scale,
                                                   u16* __restrict__ h) {
    const int b = blockIdx.x;
    const int tid = threadIdx.x;
    if (b < PREP_QKV_BLOCKS) {
        int i = b * 256 + tid;
        float4 f = ((const float4*)w_qkv)[i];
        ushort4 o;
        o.x = f2bf(f.x); o.y = f2bf(f.y); o.z = f2bf(f.z); o.w = f2bf(f.w);
        ((ushort4*)wqkv_bf)[i] = o;
    } else if (b < PREP_QKV_BLOCKS + PREP_WOUT_BLOCKS) {
        int i = (b - PREP_QKV_BLOCKS) * 256 + tid;
        int idx = i * 4;
        int row = idx >> 12;        // /4096
        int col = idx & 4095;
        ushort4 o;
        if (row < HIDDEN) {
            float4 f = *(const float4*)(w_out + (long)row * QD + col);
            o.x = f2bf(f.x); o.y = f2bf(f.y); o.z = f2bf(f.z); o.w = f2bf(f.w);
        } else {
            o.x = 0; o.y = 0; o.z = 0; o.w = 0;
        }
        ((ushort4*)wout_bf)[i] = o;
    } else {
        const int t = b - (PREP_QKV_BLOCKS + PREP_WOUT_BLOCKS);
        const float4* xr = (const float4*)(x + (long)t * HIDDEN);
        float4 v[3];
        float ss = 0.f;
        #pragma unroll
        for (int it = 0; it < 3; ++it) {
            int i4 = tid + it * 256;
            if (i4 < 720) {
                v[it] = xr[i4];
                ss += v[it].x*v[it].x + v[it].y*v[it].y + v[it].z*v[it].z + v[it].w*v[it].w;
            }
        }
        #pragma unroll
        for (int off = 32; off > 0; off >>= 1) ss += __shfl_down(ss, off);
        __shared__ float red[4];
        if ((tid & 63) == 0) red[tid >> 6] = ss;
        __syncthreads();
        float tot = red[0] + red[1] + red[2] + red[3];
        float rr = rsqrtf(tot * (1.0f / HIDDEN) + 1e-5f);
        ushort4* hr = (ushort4*)(h + (long)t * HIDDEN);
        #pragma unroll
        for (int it = 0; it < 3; ++it) {
            int i4 = tid + it * 256;
            if (i4 < 720) {
                float4 s4 = ((const float4*)scale)[i4];
                ushort4 o;
                o.x = f2bf(v[it].x * rr * s4.x);
                o.y = f2bf(v[it].y * rr * s4.y);
                o.z = f2bf(v[it].z * rr * s4.z);
                o.w = f2bf(v[it].w * rr * s4.w);
                hr[i4] = o;
            }
        }
    }
}

// ---------------- GEMM: C[M,N] = A[M,K] @ B[N,K]^T + bias (+resid) ----------------
// m97 structure widened to BK=64: two 32-col panels staged per iteration
// (8 glds16/thread), 32 MFMA between barriers -> half the barrier drains.
// K must be divisible by 64 (2880 ok, 4096 ok).
template<bool OUT_BF16, bool RES>
__global__ __launch_bounds__(256) void gemm_bt(const u16* __restrict__ A,
                                               const u16* __restrict__ B,
                                               const float* __restrict__ bias,
                                               const float* __restrict__ resid,
                                               void* __restrict__ C,
                                               int M, int N, int K, int ldc) {
    __shared__ u16 lsA[2][128 * 32];
    __shared__ u16 lsB[2][128 * 32];
    const int tid  = threadIdx.x;
    const int lane = tid & 63;
    const int wv   = tid >> 6;          // wave 0..3
    const int wm   = wv >> 1, wn = wv & 1;
    const long m0 = (long)blockIdx.y * 128;
    const long n0 = (long)blockIdx.x * 128;
    const int sr = lane >> 2;           // staging row 0..15
    const int sc = lane & 3;            // staging 16B chunk 0..3

    f32x4 acc[4][4];
    #pragma unroll
    for (int i = 0; i < 4; ++i)
        #pragma unroll
        for (int j = 0; j < 4; ++j) acc[i][j] = f32x4{0.f, 0.f, 0.f, 0.f};

    const int fr = lane & 15;           // fragment row
    const int fk = (lane >> 4) * 8;     // fragment k offset

    const u16* Abase = A + (m0 + wv * 32 + sr) * (long)K + sc * 8;
    const u16* Bbase = B + (n0 + wv * 32 + sr) * (long)K + sc * 8;
    const int ldsW = (wv * 32) * 32;    // wave's staging base within a panel
    const long rowK16 = 16 * (long)K;

    for (int k0 = 0; k0 < K; k0 += 64) {
        #pragma unroll
        for (int hh = 0; hh < 2; ++hh) {
            glds16(Abase + k0 + hh * 32,          &lsA[hh][ldsW]);
            glds16(Abase + k0 + hh * 32 + rowK16, &lsA[hh][ldsW + 16 * 32]);
            glds16(Bbase + k0 + hh * 32,          &lsB[hh][ldsW]);
            glds16(Bbase + k0 + hh * 32 + rowK16, &lsB[hh][ldsW + 16 * 32]);
        }
        __syncthreads();
        #pragma unroll
        for (int hh = 0; hh < 2; ++hh) {
            bf16x8 af[4], bfg[4];
            #pragma unroll
            for (int mi = 0; mi < 4; ++mi)
                af[mi] = *(const bf16x8*)&lsA[hh][(wm * 64 + mi * 16 + fr) * 32 + fk];
            #pragma unroll
            for (int ni = 0; ni < 4; ++ni)
                bfg[ni] = *(const bf16x8*)&lsB[hh][(wn * 64 + ni * 16 + fr) * 32 + fk];
            #pragma unroll
            for (int mi = 0; mi < 4; ++mi)
                #pragma unroll
                for (int ni = 0; ni < 4; ++ni)
                    acc[mi][ni] = __builtin_amdgcn_mfma_f32_16x16x32_bf16(af[mi], bfg[ni], acc[mi][ni], 0, 0, 0);
        }
        __syncthreads();
    }

    // epilogue: C/D layout col=lane&15, row=(lane>>4)*4+reg  [m89-verified]
    const int cr = (lane >> 4) * 4;
    const int cc = lane & 15;
    #pragma unroll
    for (int ni = 0; ni < 4; ++ni) {
        long col = n0 + wn * 64 + ni * 16 + cc;
        if (col < N) {
            float bv = bias[col];
            #pragma unroll
            for (int mi = 0; mi < 4; ++mi) {
                #pragma unroll
                for (int r2 = 0; r2 < 4; ++r2) {
                    long row = m0 + wm * 64 + mi * 16 + cr + r2;
                    float vvv = acc[mi][ni][r2] + bv;
                    if (RES) vvv += resid[row * (long)N + col];
                    if (OUT_BF16) ((u16*)C)[row * (long)ldc + col] = f2bf(vvv);
                    else          ((float*)C)[row * (long)ldc + col] = vvv;
                }
            }
        }
    }
}

// ---------------- RoPE (YaRN) ----------------
__global__ __launch_bounds__(256) void rope_kernel(const u16* __restrict__ qkv,
                                                   u16* __restrict__ qr,
                                                   u16* __restrict__ kr,
                                                   u16* __restrict__ vr) {
    const int t = blockIdx.x;
    const int tid = threadIdx.x;
    __shared__ float cs[32], sn[32];
    if (tid < 32) {
        float fi = (float)tid;
        float freq   = exp2f(17.1946032f * (fi * (1.0f / 32.0f)));   // 150000^(i/32)
        float interp = 1.0f / (32.0f * freq);
        float extra  = 1.0f / freq;
        float ramp   = (fi - 8.0927802f) * (1.0f / (17.3980220f - 8.0927802f));
        float rc     = fminf(fmaxf(ramp, 0.0f), 1.0f);               // = 1 - mask
        float invf   = interp * rc + extra * (1.0f - rc);
        float ang    = (float)t * invf;
        cs[tid] = cosf(ang) * 1.3465736f;                            // * concentration
        sn[tid] = sinf(ang) * 1.3465736f;
    }
    __syncthreads();
    const u16* row = qkv + (long)t * QKVD;
    // Q: 64 heads x 32 pairs
    for (int p = tid; p < 2048; p += 256) {
        int hd2 = p >> 5, i = p & 31;
        u32 pr = *(const u32*)(row + hd2 * 64 + 2 * i);
        float a = bflo(pr), b = bfhi(pr);
        float o1 = a * cs[i] - b * sn[i];
        float o2 = b * cs[i] + a * sn[i];
        *(u32*)(qr + (long)t * QD + hd2 * 64 + 2 * i) = (u32)f2bf(o1) | ((u32)f2bf(o2) << 16);
    }
    // K: 8 heads x 32 pairs == 256 threads; head-major layout [kv][t][64]
    {
        int kv = tid >> 5, i = tid & 31;
        u32 pr = *(const u32*)(row + QD + kv * 64 + 2 * i);
        float a = bflo(pr), b = bfhi(pr);
        float o1 = a * cs[i] - b * sn[i];
        float o2 = b * cs[i] + a * sn[i];
        *(u32*)(kr + ((long)kv * TTOK + t) * HD + 2 * i) = (u32)f2bf(o1) | ((u32)f2bf(o2) << 16);
    }
    // V copy: 8 heads x 64 = 256 u32; head-major [kv][t][64]
    {
        int kv = tid >> 5, d2 = tid & 31;
        u32 pr = *(const u32*)(row + QD + 512 + kv * 64 + 2 * d2);
        *(u32*)(vr + ((long)kv * TTOK + t) * HD + 2 * d2) = pr;
    }
}

// ---------------- MFMA sliding-window attention with sink ----------------
__global__ __launch_bounds__(256, 2) void attn_kernel(const u16* __restrict__ qr,
                                                      const u16* __restrict__ kr,
                                                      const u16* __restrict__ vr,
                                                      const float* __restrict__ sinks,
                                                      u16* __restrict__ o) {
    const int t0  = blockIdx.x * 16;
    const int h   = blockIdx.y;
    const int qhg = blockIdx.z;
    const int tid = threadIdx.x;
    const int lane = tid & 63, wv = tid >> 6;
    __shared__ __align__(16) u16 ks[144][72];    // K rows [key][64+pad]
    __shared__ __align__(16) u16 Vt[64][168];    // V^T [d][key], cols 144..159 zero
    __shared__ __align__(16) u16 P [4][16][168]; // per-wave P [token][key], cols 144..159 zero
    const u16* kb = kr + (long)h * TTOK * HD;
    const u16* vb = vr + (long)h * TTOK * HD;

    // stage K rows (coalesced)
    #pragma unroll
    for (int i = 0; i < 5; ++i) {
        int idx = i * 256 + tid;
        if (idx < 144 * 8) {
            int rr = idx >> 3, c = idx & 7;
            int tk = t0 - 128 + rr;
            int tks = tk < 0 ? 0 : tk;          // clamped; masked later
            *(uint4*)&ks[rr][c * 8] = *(const uint4*)(kb + (long)tks * HD + c * 8);
        }
    }
    // stage V transposed: thread -> one key, 8 dims per pass
    #pragma unroll
    for (int c4 = 0; c4 < 8; ++c4) {
        if (tid < 144) {
            int tk = t0 - 128 + tid;
            int tks = tk < 0 ? 0 : tk;
            uint4 v4 = *(const uint4*)(vb + (long)tks * HD + c4 * 8);
            int d0 = c4 * 8;
            Vt[d0+0][tid] = (u16)(v4.x & 0xffff); Vt[d0+1][tid] = (u16)(v4.x >> 16);
            Vt[d0+2][tid] = (u16)(v4.y & 0xffff); Vt[d0+3][tid] = (u16)(v4.y >> 16);
            Vt[d0+4][tid] = (u16)(v4.z & 0xffff); Vt[d0+5][tid] = (u16)(v4.z >> 16);
            Vt[d0+6][tid] = (u16)(v4.w & 0xffff); Vt[d0+7][tid] = (u16)(v4.w >> 16);
        }
    }
    if (tid < 128) {
        *(uint4*)&Vt[tid >> 1][144 + (tid & 1) * 8] = uint4{0, 0, 0, 0};
    }
    if (lane < 32) {
        *(uint4*)&P[wv][lane >> 1][144 + (lane & 1) * 8] = uint4{0, 0, 0, 0};
    }
    __syncthreads();

    const int qh   = qhg * 4 + wv;
    const int head = h * QMULT + qh;
    const int fr = lane & 15, fk = (lane >> 4) * 8;
    const int cr = (lane >> 4) * 4;

    const u16* qrow = qr + (long)(t0 + fr) * QD + head * HD;
    bf16x8 qf0 = *(const bf16x8*)(qrow + fk);
    bf16x8 qf1 = *(const bf16x8*)(qrow + 32 + fk);

    const int kmin = 128 - t0;          // kk >= kmin <=> key token >= 0
    float lsum[4] = {0.f, 0.f, 0.f, 0.f};

    for (int nt = 0; nt < 9; ++nt) {
        bf16x8 b0 = *(const bf16x8*)&ks[nt * 16 + fr][fk];
        bf16x8 b1 = *(const bf16x8*)&ks[nt * 16 + fr][32 + fk];
        f32x4 s = f32x4{0.f, 0.f, 0.f, 0.f};
        s = __builtin_amdgcn_mfma_f32_16x16x32_bf16(qf0, b0, s, 0, 0, 0);
        s = __builtin_amdgcn_mfma_f32_16x16x32_bf16(qf1, b1, s, 0, 0, 0);
        const int kk = nt * 16 + fr;    // C-layout col = lane&15
        #pragma unroll
        for (int r = 0; r < 4; ++r) {
            int row = cr + r;           // token index within tile
            bool valid = (kk >= row) && (kk <= row + 128) && (kk >= kmin);
            float p = valid ? __expf(s[r] * 0.125f) : 0.0f;
            lsum[r] += p;
            P[wv][row][kk] = f2bf(p);
        }
    }

    f32x4 oacc[4];
    #pragma unroll
    for (int dt = 0; dt < 4; ++dt) oacc[dt] = f32x4{0.f, 0.f, 0.f, 0.f};
    #pragma unroll
    for (int k5 = 0; k5 < 5; ++k5) {
        const int k0 = k5 * 32;
        bf16x8 pa = *(const bf16x8*)&P[wv][fr][k0 + fk];
        #pragma unroll
        for (int dt = 0; dt < 4; ++dt) {
            bf16x8 vf = *(const bf16x8*)&Vt[dt * 16 + fr][k0 + fk];
            oacc[dt] = __builtin_amdgcn_mfma_f32_16x16x32_bf16(pa, vf, oacc[dt], 0, 0, 0);
        }
    }

    #pragma unroll
    for (int r = 0; r < 4; ++r) {
        float v = lsum[r];
        v += __shfl_xor(v, 1);
        v += __shfl_xor(v, 2);
        v += __shfl_xor(v, 4);
        v += __shfl_xor(v, 8);
        lsum[r] = v;
    }
    const float sk = exp2f(sinks[head]);
    float inv[4];
    #pragma unroll
    for (int r = 0; r < 4; ++r) inv[r] = 1.0f / (lsum[r] + sk);

    #pragma unroll
    for (int dt = 0; dt < 4; ++dt) {
        #pragma unroll
        for (int r = 0; r < 4; ++r) {
            o[(long)(t0 + cr + r) * QD + head * HD + dt * 16 + fr] = f2bf(oacc[dt][r] * inv[r]);
        }
    }
}

// ---------------- launcher ----------------
extern "C" void kernel_launch(void* const* d_in, const int* in_sizes, int n_in,
                              void* d_out, int out_size, void* d_ws, size_t ws_size,
                              hipStream_t stream) {
    const float* x      = (const float*)d_in[0];
    const float* nscale = (const float*)d_in[1];
    const float* w_qkv  = (const float*)d_in[2];
    const float* b_qkv  = (const float*)d_in[3];
    const float* sinks  = (const float*)d_in[4];
    const float* w_out  = (const float*)d_in[5];
    const float* b_out  = (const float*)d_in[6];
    float* out = (float*)d_out;

    char* ws = (char*)d_ws;
    size_t off = 0;
    auto alloc = [&](size_t bytes) { void* p = ws + off; off += (bytes + 255) & ~(size_t)255; return p; };
    u16* wqkv_bf = (u16*)alloc((size_t)QKVD * HIDDEN * 2);   // 29.5 MB
    u16* wout_bf = (u16*)alloc((size_t)NPAD * QD * 2);       // 24.1 MB
    u16* h       = (u16*)alloc((size_t)TTOK * HIDDEN * 2);   // 11.8 MB
    u16* qkv     = (u16*)alloc((size_t)TTOK * QKVD * 2);     // 21.0 MB
    u16* qrot    = (u16*)alloc((size_t)TTOK * QD * 2);       // 16.8 MB
    u16* krot    = (u16*)alloc((size_t)NKV * TTOK * HD * 2); // 2.1 MB
    u16* vrot    = (u16*)alloc((size_t)NKV * TTOK * HD * 2); // 2.1 MB
    u16* attn    = qkv;  // qkv dead after rope; reuse as attention output [2048][4096]

    prep_kernel<<<PREP_QKV_BLOCKS + PREP_WOUT_BLOCKS + PREP_RMS_BLOCKS, 256, 0, stream>>>(
        w_qkv, wqkv_bf, w_out, wout_bf, x, nscale, h);
    gemm_bt<true, false><<<dim3(QKVD / 128, TTOK / 128), 256, 0, stream>>>(
        h, wqkv_bf, b_qkv, nullptr, qkv, TTOK, QKVD, HIDDEN, QKVD);
    rope_kernel<<<TTOK, 256, 0, stream>>>(qkv, qrot, krot, vrot);
    attn_kernel<<<dim3(TTOK / 16, NKV, 2), 256, 0, stream>>>(qrot, krot, vrot, sinks, attn);
    gemm_bt<false, true><<<dim3(NPAD / 128, TTOK / 128), 256, 0, stream>>>(
        attn, wout_bf, b_out, x, out, TTOK, HIDDEN, QD, HIDDEN);
}

// Round 4
// 382.454 us; speedup vs baseline: 1.4090x; 1.0440x over previous
//
#include <hip/hip_runtime.h>
#include <math.h>

typedef unsigned short u16;
typedef unsigned int   u32;
using f32x4  = __attribute__((ext_vector_type(4))) float;
using bf16x8 = __attribute__((ext_vector_type(8))) __bf16;

#define HIDDEN   2880
#define QKVD     5120
#define QD       4096
#define TTOK     2048
#define NKV      8
#define QMULT    8
#define HD       64
#define NPAD     2944   // w_out rows padded to 23*128

// prep grid partition
#define PREP_QKV_BLOCKS  14400   // QKVD*HIDDEN/4/256
#define PREP_WOUT_BLOCKS 11776   // NPAD*QD/4/256
#define PREP_RMS_BLOCKS  2048

static __device__ __forceinline__ float bflo(u32 u){ return __uint_as_float(u << 16); }
static __device__ __forceinline__ float bfhi(u32 u){ return __uint_as_float(u & 0xffff0000u); }
static __device__ __forceinline__ u16 f2bf(float f){
    u32 u = __float_as_uint(f);
    u32 r = (u + 0x7fffu + ((u >> 16) & 1u)) >> 16;
    return (u16)r;
}

static __device__ __forceinline__ void glds16(const void* g, void* l) {
    __builtin_amdgcn_global_load_lds(
        (__attribute__((address_space(1))) void*)g,
        (__attribute__((address_space(3))) void*)l,
        16, 0, 0);
}

// ---------------- fused prep: w_qkv cvt | w_out cvt+pad | rmsnorm ----------------
__global__ __launch_bounds__(256) void prep_kernel(const float* __restrict__ w_qkv,
                                                   u16* __restrict__ wqkv_bf,
                                                   const float* __restrict__ w_out,
                                                   u16* __restrict__ wout_bf,
                                                   const float* __restrict__ x,
                                                   const float* __restrict__ scale,
                                                   u16* __restrict__ h) {
    const int b = blockIdx.x;
    const int tid = threadIdx.x;
    if (b < PREP_QKV_BLOCKS) {
        int i = b * 256 + tid;
        float4 f = ((const float4*)w_qkv)[i];
        ushort4 o;
        o.x = f2bf(f.x); o.y = f2bf(f.y); o.z = f2bf(f.z); o.w = f2bf(f.w);
        ((ushort4*)wqkv_bf)[i] = o;
    } else if (b < PREP_QKV_BLOCKS + PREP_WOUT_BLOCKS) {
        int i = (b - PREP_QKV_BLOCKS) * 256 + tid;
        int idx = i * 4;
        int row = idx >> 12;        // /4096
        int col = idx & 4095;
        ushort4 o;
        if (row < HIDDEN) {
            float4 f = *(const float4*)(w_out + (long)row * QD + col);
            o.x = f2bf(f.x); o.y = f2bf(f.y); o.z = f2bf(f.z); o.w = f2bf(f.w);
        } else {
            o.x = 0; o.y = 0; o.z = 0; o.w = 0;
        }
        ((ushort4*)wout_bf)[i] = o;
    } else {
        const int t = b - (PREP_QKV_BLOCKS + PREP_WOUT_BLOCKS);
        const float4* xr = (const float4*)(x + (long)t * HIDDEN);
        float4 v[3];
        float ss = 0.f;
        #pragma unroll
        for (int it = 0; it < 3; ++it) {
            int i4 = tid + it * 256;
            if (i4 < 720) {
                v[it] = xr[i4];
                ss += v[it].x*v[it].x + v[it].y*v[it].y + v[it].z*v[it].z + v[it].w*v[it].w;
            }
        }
        #pragma unroll
        for (int off = 32; off > 0; off >>= 1) ss += __shfl_down(ss, off);
        __shared__ float red[4];
        if ((tid & 63) == 0) red[tid >> 6] = ss;
        __syncthreads();
        float tot = red[0] + red[1] + red[2] + red[3];
        float rr = rsqrtf(tot * (1.0f / HIDDEN) + 1e-5f);
        ushort4* hr = (ushort4*)(h + (long)t * HIDDEN);
        #pragma unroll
        for (int it = 0; it < 3; ++it) {
            int i4 = tid + it * 256;
            if (i4 < 720) {
                float4 s4 = ((const float4*)scale)[i4];
                ushort4 o;
                o.x = f2bf(v[it].x * rr * s4.x);
                o.y = f2bf(v[it].y * rr * s4.y);
                o.z = f2bf(v[it].z * rr * s4.z);
                o.w = f2bf(v[it].w * rr * s4.w);
                hr[i4] = o;
            }
        }
    }
}

// ---------------- GEMM: C[M,N] = A[M,K] @ B[N,K]^T + bias (+resid) ----------------
// BK=64 + explicit double-buffered glds prefetch: stage(i+1) is issued after
// the barrier but before compute(i), so the global->LDS latency overlaps the
// ds_read+MFMA phase; the next barrier's vmcnt(0) drain pays only the
// remainder. LDS 64 KB -> 2 blocks/CU (grid gives <=2.5 anyway).
template<bool OUT_BF16, bool RES>
__global__ __launch_bounds__(256) void gemm_bt(const u16* __restrict__ A,
                                               const u16* __restrict__ B,
                                               const float* __restrict__ bias,
                                               const float* __restrict__ resid,
                                               void* __restrict__ C,
                                               int M, int N, int K, int ldc) {
    __shared__ u16 lsA[2][2][128 * 32];   // [buf][panel][row*32+k]
    __shared__ u16 lsB[2][2][128 * 32];
    const int tid  = threadIdx.x;
    const int lane = tid & 63;
    const int wv   = tid >> 6;          // wave 0..3
    const int wm   = wv >> 1, wn = wv & 1;
    const long m0 = (long)blockIdx.y * 128;
    const long n0 = (long)blockIdx.x * 128;

    f32x4 acc[4][4];
    #pragma unroll
    for (int i = 0; i < 4; ++i)
        #pragma unroll
        for (int j = 0; j < 4; ++j) acc[i][j] = f32x4{0.f, 0.f, 0.f, 0.f};

    const int sr = lane >> 2;           // staging row 0..15
    const int sc = lane & 3;            // staging 16B chunk 0..3
    const int fr = lane & 15;           // fragment row
    const int fk = (lane >> 4) * 8;     // fragment k offset

    const u16* Abase = A + (m0 + wv * 32 + sr) * (long)K + sc * 8;
    const u16* Bbase = B + (n0 + wv * 32 + sr) * (long)K + sc * 8;
    const int ldsW = (wv * 32) * 32;    // wave's staging base within a panel
    const long rowK16 = 16 * (long)K;

    auto stage = [&](int k0, int buf) {
        #pragma unroll
        for (int hh = 0; hh < 2; ++hh) {
            glds16(Abase + k0 + hh * 32,          &lsA[buf][hh][ldsW]);
            glds16(Abase + k0 + hh * 32 + rowK16, &lsA[buf][hh][ldsW + 16 * 32]);
            glds16(Bbase + k0 + hh * 32,          &lsB[buf][hh][ldsW]);
            glds16(Bbase + k0 + hh * 32 + rowK16, &lsB[buf][hh][ldsW + 16 * 32]);
        }
    };

    stage(0, 0);
    int ib = 0;
    for (int k0 = 0; k0 < K; k0 += 64, ib ^= 1) {
        __syncthreads();                 // drains stage(i); protects buf ib^1 (reads of i-1 done)
        if (k0 + 64 < K) stage(k0 + 64, ib ^ 1);
        #pragma unroll
        for (int hh = 0; hh < 2; ++hh) {
            bf16x8 af[4], bfg[4];
            #pragma unroll
            for (int mi = 0; mi < 4; ++mi)
                af[mi] = *(const bf16x8*)&lsA[ib][hh][(wm * 64 + mi * 16 + fr) * 32 + fk];
            #pragma unroll
            for (int ni = 0; ni < 4; ++ni)
                bfg[ni] = *(const bf16x8*)&lsB[ib][hh][(wn * 64 + ni * 16 + fr) * 32 + fk];
            #pragma unroll
            for (int mi = 0; mi < 4; ++mi)
                #pragma unroll
                for (int ni = 0; ni < 4; ++ni)
                    acc[mi][ni] = __builtin_amdgcn_mfma_f32_16x16x32_bf16(af[mi], bfg[ni], acc[mi][ni], 0, 0, 0);
        }
    }

    // epilogue: C/D layout col=lane&15, row=(lane>>4)*4+reg  [m89-verified]
    const int cr = (lane >> 4) * 4;
    const int cc = lane & 15;
    #pragma unroll
    for (int ni = 0; ni < 4; ++ni) {
        long col = n0 + wn * 64 + ni * 16 + cc;
        if (col < N) {
            float bv = bias[col];
            #pragma unroll
            for (int mi = 0; mi < 4; ++mi) {
                #pragma unroll
                for (int r2 = 0; r2 < 4; ++r2) {
                    long row = m0 + wm * 64 + mi * 16 + cr + r2;
                    float vvv = acc[mi][ni][r2] + bv;
                    if (RES) vvv += resid[row * (long)N + col];
                    if (OUT_BF16) ((u16*)C)[row * (long)ldc + col] = f2bf(vvv);
                    else          ((float*)C)[row * (long)ldc + col] = vvv;
                }
            }
        }
    }
}

// ---------------- RoPE (YaRN) ----------------
__global__ __launch_bounds__(256) void rope_kernel(const u16* __restrict__ qkv,
                                                   u16* __restrict__ qr,
                                                   u16* __restrict__ kr,
                                                   u16* __restrict__ vr) {
    const int t = blockIdx.x;
    const int tid = threadIdx.x;
    __shared__ float cs[32], sn[32];
    if (tid < 32) {
        float fi = (float)tid;
        float freq   = exp2f(17.1946032f * (fi * (1.0f / 32.0f)));   // 150000^(i/32)
        float interp = 1.0f / (32.0f * freq);
        float extra  = 1.0f / freq;
        float ramp   = (fi - 8.0927802f) * (1.0f / (17.3980220f - 8.0927802f));
        float rc     = fminf(fmaxf(ramp, 0.0f), 1.0f);               // = 1 - mask
        float invf   = interp * rc + extra * (1.0f - rc);
        float ang    = (float)t * invf;
        cs[tid] = cosf(ang) * 1.3465736f;                            // * concentration
        sn[tid] = sinf(ang) * 1.3465736f;
    }
    __syncthreads();
    const u16* row = qkv + (long)t * QKVD;
    // Q: 64 heads x 32 pairs
    for (int p = tid; p < 2048; p += 256) {
        int hd2 = p >> 5, i = p & 31;
        u32 pr = *(const u32*)(row + hd2 * 64 + 2 * i);
        float a = bflo(pr), b = bfhi(pr);
        float o1 = a * cs[i] - b * sn[i];
        float o2 = b * cs[i] + a * sn[i];
        *(u32*)(qr + (long)t * QD + hd2 * 64 + 2 * i) = (u32)f2bf(o1) | ((u32)f2bf(o2) << 16);
    }
    // K: 8 heads x 32 pairs == 256 threads; head-major layout [kv][t][64]
    {
        int kv = tid >> 5, i = tid & 31;
        u32 pr = *(const u32*)(row + QD + kv * 64 + 2 * i);
        float a = bflo(pr), b = bfhi(pr);
        float o1 = a * cs[i] - b * sn[i];
        float o2 = b * cs[i] + a * sn[i];
        *(u32*)(kr + ((long)kv * TTOK + t) * HD + 2 * i) = (u32)f2bf(o1) | ((u32)f2bf(o2) << 16);
    }
    // V copy: 8 heads x 64 = 256 u32; head-major [kv][t][64]
    {
        int kv = tid >> 5, d2 = tid & 31;
        u32 pr = *(const u32*)(row + QD + 512 + kv * 64 + 2 * d2);
        *(u32*)(vr + ((long)kv * TTOK + t) * HD + 2 * d2) = pr;
    }
}

// ---------------- MFMA sliding-window attention with sink ----------------
__global__ __launch_bounds__(256, 2) void attn_kernel(const u16* __restrict__ qr,
                                                      const u16* __restrict__ kr,
                                                      const u16* __restrict__ vr,
                                                      const float* __restrict__ sinks,
                                                      u16* __restrict__ o) {
    const int t0  = blockIdx.x * 16;
    const int h   = blockIdx.y;
    const int qhg = blockIdx.z;
    const int tid = threadIdx.x;
    const int lane = tid & 63, wv = tid >> 6;
    __shared__ __align__(16) u16 ks[144][72];    // K rows [key][64+pad]
    __shared__ __align__(16) u16 Vt[64][168];    // V^T [d][key], cols 144..159 zero
    __shared__ __align__(16) u16 P [4][16][168]; // per-wave P [token][key], cols 144..159 zero
    const u16* kb = kr + (long)h * TTOK * HD;
    const u16* vb = vr + (long)h * TTOK * HD;

    // stage K rows (coalesced)
    #pragma unroll
    for (int i = 0; i < 5; ++i) {
        int idx = i * 256 + tid;
        if (idx < 144 * 8) {
            int rr = idx >> 3, c = idx & 7;
            int tk = t0 - 128 + rr;
            int tks = tk < 0 ? 0 : tk;          // clamped; masked later
            *(uint4*)&ks[rr][c * 8] = *(const uint4*)(kb + (long)tks * HD + c * 8);
        }
    }
    // stage V transposed: thread -> one key, 8 dims per pass
    #pragma unroll
    for (int c4 = 0; c4 < 8; ++c4) {
        if (tid < 144) {
            int tk = t0 - 128 + tid;
            int tks = tk < 0 ? 0 : tk;
            uint4 v4 = *(const uint4*)(vb + (long)tks * HD + c4 * 8);
            int d0 = c4 * 8;
            Vt[d0+0][tid] = (u16)(v4.x & 0xffff); Vt[d0+1][tid] = (u16)(v4.x >> 16);
            Vt[d0+2][tid] = (u16)(v4.y & 0xffff); Vt[d0+3][tid] = (u16)(v4.y >> 16);
            Vt[d0+4][tid] = (u16)(v4.z & 0xffff); Vt[d0+5][tid] = (u16)(v4.z >> 16);
            Vt[d0+6][tid] = (u16)(v4.w & 0xffff); Vt[d0+7][tid] = (u16)(v4.w >> 16);
        }
    }
    if (tid < 128) {
        *(uint4*)&Vt[tid >> 1][144 + (tid & 1) * 8] = uint4{0, 0, 0, 0};
    }
    if (lane < 32) {
        *(uint4*)&P[wv][lane >> 1][144 + (lane & 1) * 8] = uint4{0, 0, 0, 0};
    }
    __syncthreads();

    const int qh   = qhg * 4 + wv;
    const int head = h * QMULT + qh;
    const int fr = lane & 15, fk = (lane >> 4) * 8;
    const int cr = (lane >> 4) * 4;

    const u16* qrow = qr + (long)(t0 + fr) * QD + head * HD;
    bf16x8 qf0 = *(const bf16x8*)(qrow + fk);
    bf16x8 qf1 = *(const bf16x8*)(qrow + 32 + fk);

    const int kmin = 128 - t0;          // kk >= kmin <=> key token >= 0
    float lsum[4] = {0.f, 0.f, 0.f, 0.f};

    for (int nt = 0; nt < 9; ++nt) {
        bf16x8 b0 = *(const bf16x8*)&ks[nt * 16 + fr][fk];
        bf16x8 b1 = *(const bf16x8*)&ks[nt * 16 + fr][32 + fk];
        f32x4 s = f32x4{0.f, 0.f, 0.f, 0.f};
        s = __builtin_amdgcn_mfma_f32_16x16x32_bf16(qf0, b0, s, 0, 0, 0);
        s = __builtin_amdgcn_mfma_f32_16x16x32_bf16(qf1, b1, s, 0, 0, 0);
        const int kk = nt * 16 + fr;    // C-layout col = lane&15
        #pragma unroll
        for (int r = 0; r < 4; ++r) {
            int row = cr + r;           // token index within tile
            bool valid = (kk >= row) && (kk <= row + 128) && (kk >= kmin);
            float p = valid ? __expf(s[r] * 0.125f) : 0.0f;
            lsum[r] += p;
            P[wv][row][kk] = f2bf(p);
        }
    }

    f32x4 oacc[4];
    #pragma unroll
    for (int dt = 0; dt < 4; ++dt) oacc[dt] = f32x4{0.f, 0.f, 0.f, 0.f};
    #pragma unroll
    for (int k5 = 0; k5 < 5; ++k5) {
        const int k0 = k5 * 32;
        bf16x8 pa = *(const bf16x8*)&P[wv][fr][k0 + fk];
        #pragma unroll
        for (int dt = 0; dt < 4; ++dt) {
            bf16x8 vf = *(const bf16x8*)&Vt[dt * 16 + fr][k0 + fk];
            oacc[dt] = __builtin_amdgcn_mfma_f32_16x16x32_bf16(pa, vf, oacc[dt], 0, 0, 0);
        }
    }

    #pragma unroll
    for (int r = 0; r < 4; ++r) {
        float v = lsum[r];
        v += __shfl_xor(v, 1);
        v += __shfl_xor(v, 2);
        v += __shfl_xor(v, 4);
        v += __shfl_xor(v, 8);
        lsum[r] = v;
    }
    const float sk = exp2f(sinks[head]);
    float inv[4];
    #pragma unroll
    for (int r = 0; r < 4; ++r) inv[r] = 1.0f / (lsum[r] + sk);

    #pragma unroll
    for (int dt = 0; dt < 4; ++dt) {
        #pragma unroll
        for (int r = 0; r < 4; ++r) {
            o[(long)(t0 + cr + r) * QD + head * HD + dt * 16 + fr] = f2bf(oacc[dt][r] * inv[r]);
        }
    }
}

// ---------------- launcher ----------------
extern "C" void kernel_launch(void* const* d_in, const int* in_sizes, int n_in,
                              void* d_out, int out_size, void* d_ws, size_t ws_size,
                              hipStream_t stream) {
    const float* x      = (const float*)d_in[0];
    const float* nscale = (const float*)d_in[1];
    const float* w_qkv  = (const float*)d_in[2];
    const float* b_qkv  = (const float*)d_in[3];
    const float* sinks  = (const float*)d_in[4];
    const float* w_out  = (const float*)d_in[5];
    const float* b_out  = (const float*)d_in[6];
    float* out = (float*)d_out;

    char* ws = (char*)d_ws;
    size_t off = 0;
    auto alloc = [&](size_t bytes) { void* p = ws + off; off += (bytes + 255) & ~(size_t)255; return p; };
    u16* wqkv_bf = (u16*)alloc((size_t)QKVD * HIDDEN * 2);   // 29.5 MB
    u16* wout_bf = (u16*)alloc((size_t)NPAD * QD * 2);       // 24.1 MB
    u16* h       = (u16*)alloc((size_t)TTOK * HIDDEN * 2);   // 11.8 MB
    u16* qkv     = (u16*)alloc((size_t)TTOK * QKVD * 2);     // 21.0 MB
    u16* qrot    = (u16*)alloc((size_t)TTOK * QD * 2);       // 16.8 MB
    u16* krot    = (u16*)alloc((size_t)NKV * TTOK * HD * 2); // 2.1 MB
    u16* vrot    = (u16*)alloc((size_t)NKV * TTOK * HD * 2); // 2.1 MB
    u16* attn    = qkv;  // qkv dead after rope; reuse as attention output [2048][4096]

    prep_kernel<<<PREP_QKV_BLOCKS + PREP_WOUT_BLOCKS + PREP_RMS_BLOCKS, 256, 0, stream>>>(
        w_qkv, wqkv_bf, w_out, wout_bf, x, nscale, h);
    gemm_bt<true, false><<<dim3(QKVD / 128, TTOK / 128), 256, 0, stream>>>(
        h, wqkv_bf, b_qkv, nullptr, qkv, TTOK, QKVD, HIDDEN, QKVD);
    rope_kernel<<<TTOK, 256, 0, stream>>>(qkv, qrot, krot, vrot);
    attn_kernel<<<dim3(TTOK / 16, NKV, 2), 256, 0, stream>>>(qrot, krot, vrot, sinks, attn);
    gemm_bt<false, true><<<dim3(NPAD / 128, TTOK / 128), 256, 0, stream>>>(
        attn, wout_bf, b_out, x, out, TTOK, HIDDEN, QD, HIDDEN);
}

// Round 5
// 380.425 us; speedup vs baseline: 1.4166x; 1.0053x over previous
//
#include <hip/hip_runtime.h>
#include <math.h>

typedef unsigned short u16;
typedef unsigned int   u32;
using f32x4  = __attribute__((ext_vector_type(4))) float;
using bf16x8 = __attribute__((ext_vector_type(8))) __bf16;

#define HIDDEN   2880
#define QKVD     5120
#define QD       4096
#define TTOK     2048
#define NKV      8
#define QMULT    8
#define HD       64
#define NPAD     2944   // w_out rows padded to 23*128

// prep grid partition
#define PREP_QKV_BLOCKS  14400   // QKVD*HIDDEN/4/256
#define PREP_WOUT_BLOCKS 11776   // NPAD*QD/4/256
#define PREP_RMS_BLOCKS  2048

static __device__ __forceinline__ float bflo(u32 u){ return __uint_as_float(u << 16); }
static __device__ __forceinline__ float bfhi(u32 u){ return __uint_as_float(u & 0xffff0000u); }
static __device__ __forceinline__ u16 f2bf(float f){
    u32 u = __float_as_uint(f);
    u32 r = (u + 0x7fffu + ((u >> 16) & 1u)) >> 16;
    return (u16)r;
}

static __device__ __forceinline__ void glds16(const void* g, void* l) {
    __builtin_amdgcn_global_load_lds(
        (__attribute__((address_space(1))) void*)g,
        (__attribute__((address_space(3))) void*)l,
        16, 0, 0);
}

// ---------------- fused prep: w_qkv cvt | w_out cvt+pad | rmsnorm ----------------
__global__ __launch_bounds__(256) void prep_kernel(const float* __restrict__ w_qkv,
                                                   u16* __restrict__ wqkv_bf,
                                                   const float* __restrict__ w_out,
                                                   u16* __restrict__ wout_bf,
                                                   const float* __restrict__ x,
                                                   const float* __restrict__ scale,
                                                   u16* __restrict__ h) {
    const int b = blockIdx.x;
    const int tid = threadIdx.x;
    if (b < PREP_QKV_BLOCKS) {
        int i = b * 256 + tid;
        float4 f = ((const float4*)w_qkv)[i];
        ushort4 o;
        o.x = f2bf(f.x); o.y = f2bf(f.y); o.z = f2bf(f.z); o.w = f2bf(f.w);
        ((ushort4*)wqkv_bf)[i] = o;
    } else if (b < PREP_QKV_BLOCKS + PREP_WOUT_BLOCKS) {
        int i = (b - PREP_QKV_BLOCKS) * 256 + tid;
        int idx = i * 4;
        int row = idx >> 12;        // /4096
        int col = idx & 4095;
        ushort4 o;
        if (row < HIDDEN) {
            float4 f = *(const float4*)(w_out + (long)row * QD + col);
            o.x = f2bf(f.x); o.y = f2bf(f.y); o.z = f2bf(f.z); o.w = f2bf(f.w);
        } else {
            o.x = 0; o.y = 0; o.z = 0; o.w = 0;
        }
        ((ushort4*)wout_bf)[i] = o;
    } else {
        const int t = b - (PREP_QKV_BLOCKS + PREP_WOUT_BLOCKS);
        const float4* xr = (const float4*)(x + (long)t * HIDDEN);
        float4 v[3];
        float ss = 0.f;
        #pragma unroll
        for (int it = 0; it < 3; ++it) {
            int i4 = tid + it * 256;
            if (i4 < 720) {
                v[it] = xr[i4];
                ss += v[it].x*v[it].x + v[it].y*v[it].y + v[it].z*v[it].z + v[it].w*v[it].w;
            }
        }
        #pragma unroll
        for (int off = 32; off > 0; off >>= 1) ss += __shfl_down(ss, off);
        __shared__ float red[4];
        if ((tid & 63) == 0) red[tid >> 6] = ss;
        __syncthreads();
        float tot = red[0] + red[1] + red[2] + red[3];
        float rr = rsqrtf(tot * (1.0f / HIDDEN) + 1e-5f);
        ushort4* hr = (ushort4*)(h + (long)t * HIDDEN);
        #pragma unroll
        for (int it = 0; it < 3; ++it) {
            int i4 = tid + it * 256;
            if (i4 < 720) {
                float4 s4 = ((const float4*)scale)[i4];
                ushort4 o;
                o.x = f2bf(v[it].x * rr * s4.x);
                o.y = f2bf(v[it].y * rr * s4.y);
                o.z = f2bf(v[it].z * rr * s4.z);
                o.w = f2bf(v[it].w * rr * s4.w);
                hr[i4] = o;
            }
        }
    }
}

// ---------------- GEMM: C[M,N] = A[M,K] @ B[N,K]^T + bias (+resid) ----------------
// 64x128 tile (was 128x128): halves per-block work to double the grid, so
// 2.9-5 blocks/CU (LDS 48 KB -> 3 resident) hide the glds latency via TLP —
// R3/R4 showed 1.4 blocks/CU leaves the ~900cyc round-trip exposed.
// BK=64 double-buffered prefetch kept. Wave wv owns N-cols [wv*32, wv*32+32).
template<bool OUT_BF16, bool RES>
__global__ __launch_bounds__(256) void gemm_bt(const u16* __restrict__ A,
                                               const u16* __restrict__ B,
                                               const float* __restrict__ bias,
                                               const float* __restrict__ resid,
                                               void* __restrict__ C,
                                               int M, int N, int K, int ldc) {
    __shared__ u16 lsA[2][2][64 * 32];    // [buf][panel][row*32+k]  16 KB
    __shared__ u16 lsB[2][2][128 * 32];   //                         32 KB
    const int tid  = threadIdx.x;
    const int lane = tid & 63;
    const int wv   = tid >> 6;          // wave 0..3
    const long m0 = (long)blockIdx.y * 64;
    const long n0 = (long)blockIdx.x * 128;

    f32x4 acc[4][2];
    #pragma unroll
    for (int i = 0; i < 4; ++i)
        #pragma unroll
        for (int j = 0; j < 2; ++j) acc[i][j] = f32x4{0.f, 0.f, 0.f, 0.f};

    const int sr = lane >> 2;           // staging row 0..15
    const int sc = lane & 3;            // staging 16B chunk 0..3
    const int fr = lane & 15;           // fragment row
    const int fk = (lane >> 4) * 8;     // fragment k offset

    const u16* Abase = A + (m0 + wv * 16 + sr) * (long)K + sc * 8;
    const u16* Bbase = B + (n0 + wv * 32 + sr) * (long)K + sc * 8;
    const long rowK16 = 16 * (long)K;

    auto stage = [&](int k0, int buf) {
        #pragma unroll
        for (int hh = 0; hh < 2; ++hh) {
            glds16(Abase + k0 + hh * 32,          &lsA[buf][hh][(wv * 16) * 32]);
            glds16(Bbase + k0 + hh * 32,          &lsB[buf][hh][(wv * 32) * 32]);
            glds16(Bbase + k0 + hh * 32 + rowK16, &lsB[buf][hh][(wv * 32 + 16) * 32]);
        }
    };

    stage(0, 0);
    int ib = 0;
    for (int k0 = 0; k0 < K; k0 += 64, ib ^= 1) {
        __syncthreads();                 // drains stage(i); protects buf ib^1
        if (k0 + 64 < K) stage(k0 + 64, ib ^ 1);
        #pragma unroll
        for (int hh = 0; hh < 2; ++hh) {
            bf16x8 af[4], bfg[2];
            #pragma unroll
            for (int mi = 0; mi < 4; ++mi)
                af[mi] = *(const bf16x8*)&lsA[ib][hh][(mi * 16 + fr) * 32 + fk];
            #pragma unroll
            for (int ni = 0; ni < 2; ++ni)
                bfg[ni] = *(const bf16x8*)&lsB[ib][hh][(wv * 32 + ni * 16 + fr) * 32 + fk];
            #pragma unroll
            for (int mi = 0; mi < 4; ++mi)
                #pragma unroll
                for (int ni = 0; ni < 2; ++ni)
                    acc[mi][ni] = __builtin_amdgcn_mfma_f32_16x16x32_bf16(af[mi], bfg[ni], acc[mi][ni], 0, 0, 0);
        }
    }

    // epilogue: C/D layout col=lane&15, row=(lane>>4)*4+reg  [m89-verified]
    const int cr = (lane >> 4) * 4;
    const int cc = lane & 15;
    #pragma unroll
    for (int ni = 0; ni < 2; ++ni) {
        long col = n0 + wv * 32 + ni * 16 + cc;
        if (col < N) {
            float bv = bias[col];
            #pragma unroll
            for (int mi = 0; mi < 4; ++mi) {
                #pragma unroll
                for (int r2 = 0; r2 < 4; ++r2) {
                    long row = m0 + mi * 16 + cr + r2;
                    float vvv = acc[mi][ni][r2] + bv;
                    if (RES) vvv += resid[row * (long)N + col];
                    if (OUT_BF16) ((u16*)C)[row * (long)ldc + col] = f2bf(vvv);
                    else          ((float*)C)[row * (long)ldc + col] = vvv;
                }
            }
        }
    }
}

// ---------------- RoPE (YaRN) ----------------
__global__ __launch_bounds__(256) void rope_kernel(const u16* __restrict__ qkv,
                                                   u16* __restrict__ qr,
                                                   u16* __restrict__ kr,
                                                   u16* __restrict__ vr) {
    const int t = blockIdx.x;
    const int tid = threadIdx.x;
    __shared__ float cs[32], sn[32];
    if (tid < 32) {
        float fi = (float)tid;
        float freq   = exp2f(17.1946032f * (fi * (1.0f / 32.0f)));   // 150000^(i/32)
        float interp = 1.0f / (32.0f * freq);
        float extra  = 1.0f / freq;
        float ramp   = (fi - 8.0927802f) * (1.0f / (17.3980220f - 8.0927802f));
        float rc     = fminf(fmaxf(ramp, 0.0f), 1.0f);               // = 1 - mask
        float invf   = interp * rc + extra * (1.0f - rc);
        float ang    = (float)t * invf;
        cs[tid] = cosf(ang) * 1.3465736f;                            // * concentration
        sn[tid] = sinf(ang) * 1.3465736f;
    }
    __syncthreads();
    const u16* row = qkv + (long)t * QKVD;
    // Q: 64 heads x 32 pairs
    for (int p = tid; p < 2048; p += 256) {
        int hd2 = p >> 5, i = p & 31;
        u32 pr = *(const u32*)(row + hd2 * 64 + 2 * i);
        float a = bflo(pr), b = bfhi(pr);
        float o1 = a * cs[i] - b * sn[i];
        float o2 = b * cs[i] + a * sn[i];
        *(u32*)(qr + (long)t * QD + hd2 * 64 + 2 * i) = (u32)f2bf(o1) | ((u32)f2bf(o2) << 16);
    }
    // K: 8 heads x 32 pairs == 256 threads; head-major layout [kv][t][64]
    {
        int kv = tid >> 5, i = tid & 31;
        u32 pr = *(const u32*)(row + QD + kv * 64 + 2 * i);
        float a = bflo(pr), b = bfhi(pr);
        float o1 = a * cs[i] - b * sn[i];
        float o2 = b * cs[i] + a * sn[i];
        *(u32*)(kr + ((long)kv * TTOK + t) * HD + 2 * i) = (u32)f2bf(o1) | ((u32)f2bf(o2) << 16);
    }
    // V copy: 8 heads x 64 = 256 u32; head-major [kv][t][64]
    {
        int kv = tid >> 5, d2 = tid & 31;
        u32 pr = *(const u32*)(row + QD + 512 + kv * 64 + 2 * d2);
        *(u32*)(vr + ((long)kv * TTOK + t) * HD + 2 * d2) = pr;
    }
}

// ---------------- MFMA sliding-window attention with sink ----------------
__global__ __launch_bounds__(256, 2) void attn_kernel(const u16* __restrict__ qr,
                                                      const u16* __restrict__ kr,
                                                      const u16* __restrict__ vr,
                                                      const float* __restrict__ sinks,
                                                      u16* __restrict__ o) {
    const int t0  = blockIdx.x * 16;
    const int h   = blockIdx.y;
    const int qhg = blockIdx.z;
    const int tid = threadIdx.x;
    const int lane = tid & 63, wv = tid >> 6;
    __shared__ __align__(16) u16 ks[144][72];    // K rows [key][64+pad]
    __shared__ __align__(16) u16 Vt[64][168];    // V^T [d][key], cols 144..159 zero
    __shared__ __align__(16) u16 P [4][16][168]; // per-wave P [token][key], cols 144..159 zero
    const u16* kb = kr + (long)h * TTOK * HD;
    const u16* vb = vr + (long)h * TTOK * HD;

    // stage K rows (coalesced)
    #pragma unroll
    for (int i = 0; i < 5; ++i) {
        int idx = i * 256 + tid;
        if (idx < 144 * 8) {
            int rr = idx >> 3, c = idx & 7;
            int tk = t0 - 128 + rr;
            int tks = tk < 0 ? 0 : tk;          // clamped; masked later
            *(uint4*)&ks[rr][c * 8] = *(const uint4*)(kb + (long)tks * HD + c * 8);
        }
    }
    // stage V transposed: thread -> one key, 8 dims per pass
    #pragma unroll
    for (int c4 = 0; c4 < 8; ++c4) {
        if (tid < 144) {
            int tk = t0 - 128 + tid;
            int tks = tk < 0 ? 0 : tk;
            uint4 v4 = *(const uint4*)(vb + (long)tks * HD + c4 * 8);
            int d0 = c4 * 8;
            Vt[d0+0][tid] = (u16)(v4.x & 0xffff); Vt[d0+1][tid] = (u16)(v4.x >> 16);
            Vt[d0+2][tid] = (u16)(v4.y & 0xffff); Vt[d0+3][tid] = (u16)(v4.y >> 16);
            Vt[d0+4][tid] = (u16)(v4.z & 0xffff); Vt[d0+5][tid] = (u16)(v4.z >> 16);
            Vt[d0+6][tid] = (u16)(v4.w & 0xffff); Vt[d0+7][tid] = (u16)(v4.w >> 16);
        }
    }
    if (tid < 128) {
        *(uint4*)&Vt[tid >> 1][144 + (tid & 1) * 8] = uint4{0, 0, 0, 0};
    }
    if (lane < 32) {
        *(uint4*)&P[wv][lane >> 1][144 + (lane & 1) * 8] = uint4{0, 0, 0, 0};
    }
    __syncthreads();

    const int qh   = qhg * 4 + wv;
    const int head = h * QMULT + qh;
    const int fr = lane & 15, fk = (lane >> 4) * 8;
    const int cr = (lane >> 4) * 4;

    const u16* qrow = qr + (long)(t0 + fr) * QD + head * HD;
    bf16x8 qf0 = *(const bf16x8*)(qrow + fk);
    bf16x8 qf1 = *(const bf16x8*)(qrow + 32 + fk);

    const int kmin = 128 - t0;          // kk >= kmin <=> key token >= 0
    float lsum[4] = {0.f, 0.f, 0.f, 0.f};

    for (int nt = 0; nt < 9; ++nt) {
        bf16x8 b0 = *(const bf16x8*)&ks[nt * 16 + fr][fk];
        bf16x8 b1 = *(const bf16x8*)&ks[nt * 16 + fr][32 + fk];
        f32x4 s = f32x4{0.f, 0.f, 0.f, 0.f};
        s = __builtin_amdgcn_mfma_f32_16x16x32_bf16(qf0, b0, s, 0, 0, 0);
        s = __builtin_amdgcn_mfma_f32_16x16x32_bf16(qf1, b1, s, 0, 0, 0);
        const int kk = nt * 16 + fr;    // C-layout col = lane&15
        #pragma unroll
        for (int r = 0; r < 4; ++r) {
            int row = cr + r;           // token index within tile
            bool valid = (kk >= row) && (kk <= row + 128) && (kk >= kmin);
            float p = valid ? __expf(s[r] * 0.125f) : 0.0f;
            lsum[r] += p;
            P[wv][row][kk] = f2bf(p);
        }
    }

    f32x4 oacc[4];
    #pragma unroll
    for (int dt = 0; dt < 4; ++dt) oacc[dt] = f32x4{0.f, 0.f, 0.f, 0.f};
    #pragma unroll
    for (int k5 = 0; k5 < 5; ++k5) {
        const int k0 = k5 * 32;
        bf16x8 pa = *(const bf16x8*)&P[wv][fr][k0 + fk];
        #pragma unroll
        for (int dt = 0; dt < 4; ++dt) {
            bf16x8 vf = *(const bf16x8*)&Vt[dt * 16 + fr][k0 + fk];
            oacc[dt] = __builtin_amdgcn_mfma_f32_16x16x32_bf16(pa, vf, oacc[dt], 0, 0, 0);
        }
    }

    #pragma unroll
    for (int r = 0; r < 4; ++r) {
        float v = lsum[r];
        v += __shfl_xor(v, 1);
        v += __shfl_xor(v, 2);
        v += __shfl_xor(v, 4);
        v += __shfl_xor(v, 8);
        lsum[r] = v;
    }
    const float sk = exp2f(sinks[head]);
    float inv[4];
    #pragma unroll
    for (int r = 0; r < 4; ++r) inv[r] = 1.0f / (lsum[r] + sk);

    #pragma unroll
    for (int dt = 0; dt < 4; ++dt) {
        #pragma unroll
        for (int r = 0; r < 4; ++r) {
            o[(long)(t0 + cr + r) * QD + head * HD + dt * 16 + fr] = f2bf(oacc[dt][r] * inv[r]);
        }
    }
}

// ---------------- launcher ----------------
extern "C" void kernel_launch(void* const* d_in, const int* in_sizes, int n_in,
                              void* d_out, int out_size, void* d_ws, size_t ws_size,
                              hipStream_t stream) {
    const float* x      = (const float*)d_in[0];
    const float* nscale = (const float*)d_in[1];
    const float* w_qkv  = (const float*)d_in[2];
    const float* b_qkv  = (const float*)d_in[3];
    const float* sinks  = (const float*)d_in[4];
    const float* w_out  = (const float*)d_in[5];
    const float* b_out  = (const float*)d_in[6];
    float* out = (float*)d_out;

    char* ws = (char*)d_ws;
    size_t off = 0;
    auto alloc = [&](size_t bytes) { void* p = ws + off; off += (bytes + 255) & ~(size_t)255; return p; };
    u16* wqkv_bf = (u16*)alloc((size_t)QKVD * HIDDEN * 2);   // 29.5 MB
    u16* wout_bf = (u16*)alloc((size_t)NPAD * QD * 2);       // 24.1 MB
    u16* h       = (u16*)alloc((size_t)TTOK * HIDDEN * 2);   // 11.8 MB
    u16* qkv     = (u16*)alloc((size_t)TTOK * QKVD * 2);     // 21.0 MB
    u16* qrot    = (u16*)alloc((size_t)TTOK * QD * 2);       // 16.8 MB
    u16* krot    = (u16*)alloc((size_t)NKV * TTOK * HD * 2); // 2.1 MB
    u16* vrot    = (u16*)alloc((size_t)NKV * TTOK * HD * 2); // 2.1 MB
    u16* attn    = qkv;  // qkv dead after rope; reuse as attention output [2048][4096]

    prep_kernel<<<PREP_QKV_BLOCKS + PREP_WOUT_BLOCKS + PREP_RMS_BLOCKS, 256, 0, stream>>>(
        w_qkv, wqkv_bf, w_out, wout_bf, x, nscale, h);
    gemm_bt<true, false><<<dim3(QKVD / 128, TTOK / 64), 256, 0, stream>>>(
        h, wqkv_bf, b_qkv, nullptr, qkv, TTOK, QKVD, HIDDEN, QKVD);
    rope_kernel<<<TTOK, 256, 0, stream>>>(qkv, qrot, krot, vrot);
    attn_kernel<<<dim3(TTOK / 16, NKV, 2), 256, 0, stream>>>(qrot, krot, vrot, sinks, attn);
    gemm_bt<false, true><<<dim3(NPAD / 128, TTOK / 64), 256, 0, stream>>>(
        attn, wout_bf, b_out, x, out, TTOK, HIDDEN, QD, HIDDEN);
}

// Round 6
// 354.159 us; speedup vs baseline: 1.5216x; 1.0742x over previous
//
#include <hip/hip_runtime.h>
#include <math.h>

typedef unsigned short u16;
typedef unsigned int   u32;
using f32x4  = __attribute__((ext_vector_type(4))) float;
using bf16x8 = __attribute__((ext_vector_type(8))) __bf16;

#define HIDDEN   2880
#define QKVD     5120
#define QD       4096
#define TTOK     2048
#define NKV      8
#define QMULT    8
#define HD       64
#define NPAD     2944   // w_out rows padded to 23*128

// prep grid partition
#define PREP_QKV_BLOCKS  14400   // QKVD*HIDDEN/4/256
#define PREP_WOUT_BLOCKS 11776   // NPAD*QD/4/256
#define PREP_RMS_BLOCKS  2048

static __device__ __forceinline__ float bflo(u32 u){ return __uint_as_float(u << 16); }
static __device__ __forceinline__ float bfhi(u32 u){ return __uint_as_float(u & 0xffff0000u); }
static __device__ __forceinline__ u16 f2bf(float f){
    u32 u = __float_as_uint(f);
    u32 r = (u + 0x7fffu + ((u >> 16) & 1u)) >> 16;
    return (u16)r;
}

static __device__ __forceinline__ void glds16(const void* g, void* l) {
    __builtin_amdgcn_global_load_lds(
        (__attribute__((address_space(1))) void*)g,
        (__attribute__((address_space(3))) void*)l,
        16, 0, 0);
}

// ---------------- fused prep: w_qkv cvt | w_out cvt+pad | rmsnorm ----------------
__global__ __launch_bounds__(256) void prep_kernel(const float* __restrict__ w_qkv,
                                                   u16* __restrict__ wqkv_bf,
                                                   const float* __restrict__ w_out,
                                                   u16* __restrict__ wout_bf,
                                                   const float* __restrict__ x,
                                                   const float* __restrict__ scale,
                                                   u16* __restrict__ h) {
    const int b = blockIdx.x;
    const int tid = threadIdx.x;
    if (b < PREP_QKV_BLOCKS) {
        int i = b * 256 + tid;
        float4 f = ((const float4*)w_qkv)[i];
        ushort4 o;
        o.x = f2bf(f.x); o.y = f2bf(f.y); o.z = f2bf(f.z); o.w = f2bf(f.w);
        ((ushort4*)wqkv_bf)[i] = o;
    } else if (b < PREP_QKV_BLOCKS + PREP_WOUT_BLOCKS) {
        int i = (b - PREP_QKV_BLOCKS) * 256 + tid;
        int idx = i * 4;
        int row = idx >> 12;        // /4096
        int col = idx & 4095;
        ushort4 o;
        if (row < HIDDEN) {
            float4 f = *(const float4*)(w_out + (long)row * QD + col);
            o.x = f2bf(f.x); o.y = f2bf(f.y); o.z = f2bf(f.z); o.w = f2bf(f.w);
        } else {
            o.x = 0; o.y = 0; o.z = 0; o.w = 0;
        }
        ((ushort4*)wout_bf)[i] = o;
    } else {
        const int t = b - (PREP_QKV_BLOCKS + PREP_WOUT_BLOCKS);
        const float4* xr = (const float4*)(x + (long)t * HIDDEN);
        float4 v[3];
        float ss = 0.f;
        #pragma unroll
        for (int it = 0; it < 3; ++it) {
            int i4 = tid + it * 256;
            if (i4 < 720) {
                v[it] = xr[i4];
                ss += v[it].x*v[it].x + v[it].y*v[it].y + v[it].z*v[it].z + v[it].w*v[it].w;
            }
        }
        #pragma unroll
        for (int off = 32; off > 0; off >>= 1) ss += __shfl_down(ss, off);
        __shared__ float red[4];
        if ((tid & 63) == 0) red[tid >> 6] = ss;
        __syncthreads();
        float tot = red[0] + red[1] + red[2] + red[3];
        float rr = rsqrtf(tot * (1.0f / HIDDEN) + 1e-5f);
        ushort4* hr = (ushort4*)(h + (long)t * HIDDEN);
        #pragma unroll
        for (int it = 0; it < 3; ++it) {
            int i4 = tid + it * 256;
            if (i4 < 720) {
                float4 s4 = ((const float4*)scale)[i4];
                ushort4 o;
                o.x = f2bf(v[it].x * rr * s4.x);
                o.y = f2bf(v[it].y * rr * s4.y);
                o.z = f2bf(v[it].z * rr * s4.z);
                o.w = f2bf(v[it].w * rr * s4.w);
                hr[i4] = o;
            }
        }
    }
}

// ---------------- split-K partial GEMM: Cz[M,N] = A[M,K(kb:ke)] @ B[N,K]^T ----------
// 128x128 tile (best bytes/flop: FETCH 77.8MB in R4), BK=32 double-buffered
// prefetch, LDS 32 KB -> 4-5 resident blocks/CU. Occupancy comes from
// blockIdx.z (split-K), NOT smaller tiles (R5: 64-tile tripled HBM traffic).
// Partials in bf16 (partial sums O(1); quant err ~0.003 << budget).
__global__ __launch_bounds__(256) void gemm_bt_part(const u16* __restrict__ A,
                                                    const u16* __restrict__ B,
                                                    u16* __restrict__ C0,
                                                    int N, int K, int ksplit) {
    __shared__ u16 lsA[2][128 * 32];
    __shared__ u16 lsB[2][128 * 32];
    const int tid  = threadIdx.x;
    const int lane = tid & 63;
    const int wv   = tid >> 6;          // wave 0..3
    const int wm   = wv >> 1, wn = wv & 1;
    const long m0 = (long)blockIdx.y * 128;
    const long n0 = (long)blockIdx.x * 128;
    const int kb = blockIdx.z * ksplit;
    const int ke = kb + ksplit;
    u16* C = C0 + (size_t)blockIdx.z * ((size_t)TTOK * N);

    f32x4 acc[4][4];
    #pragma unroll
    for (int i = 0; i < 4; ++i)
        #pragma unroll
        for (int j = 0; j < 4; ++j) acc[i][j] = f32x4{0.f, 0.f, 0.f, 0.f};

    const int sr = lane >> 2;           // staging row 0..15
    const int sc = lane & 3;            // staging 16B chunk 0..3
    const int fr = lane & 15;           // fragment row
    const int fk = (lane >> 4) * 8;     // fragment k offset

    const u16* Abase = A + (m0 + wv * 32 + sr) * (long)K + sc * 8;
    const u16* Bbase = B + (n0 + wv * 32 + sr) * (long)K + sc * 8;
    const int ldsW = (wv * 32) * 32;
    const long rowK16 = 16 * (long)K;

    auto stage = [&](int k0, int buf) {
        glds16(Abase + k0,          &lsA[buf][ldsW]);
        glds16(Abase + k0 + rowK16, &lsA[buf][ldsW + 512]);
        glds16(Bbase + k0,          &lsB[buf][ldsW]);
        glds16(Bbase + k0 + rowK16, &lsB[buf][ldsW + 512]);
    };

    stage(kb, 0);
    int ib = 0;
    for (int k0 = kb; k0 < ke; k0 += 32, ib ^= 1) {
        __syncthreads();                 // drains stage(i); protects buf ib^1
        if (k0 + 32 < ke) stage(k0 + 32, ib ^ 1);
        bf16x8 af[4], bfg[4];
        #pragma unroll
        for (int mi = 0; mi < 4; ++mi)
            af[mi] = *(const bf16x8*)&lsA[ib][(wm * 64 + mi * 16 + fr) * 32 + fk];
        #pragma unroll
        for (int ni = 0; ni < 4; ++ni)
            bfg[ni] = *(const bf16x8*)&lsB[ib][(wn * 64 + ni * 16 + fr) * 32 + fk];
        #pragma unroll
        for (int mi = 0; mi < 4; ++mi)
            #pragma unroll
            for (int ni = 0; ni < 4; ++ni)
                acc[mi][ni] = __builtin_amdgcn_mfma_f32_16x16x32_bf16(af[mi], bfg[ni], acc[mi][ni], 0, 0, 0);
    }

    // epilogue: C/D layout col=lane&15, row=(lane>>4)*4+reg  [m89-verified]
    const int cr = (lane >> 4) * 4;
    const int cc = lane & 15;
    #pragma unroll
    for (int ni = 0; ni < 4; ++ni) {
        long col = n0 + wn * 64 + ni * 16 + cc;
        #pragma unroll
        for (int mi = 0; mi < 4; ++mi) {
            #pragma unroll
            for (int r2 = 0; r2 < 4; ++r2) {
                long row = m0 + wm * 64 + mi * 16 + cr + r2;
                C[row * (long)N + col] = f2bf(acc[mi][ni][r2]);
            }
        }
    }
}

// ---------------- RoPE (YaRN), consumes GEMM1 split-K partials + bias ----------------
__global__ __launch_bounds__(256) void rope_kernel(const u16* __restrict__ p1a,
                                                   const u16* __restrict__ p1b,
                                                   const float* __restrict__ b_qkv,
                                                   u16* __restrict__ qr,
                                                   u16* __restrict__ kr,
                                                   u16* __restrict__ vr) {
    const int t = blockIdx.x;
    const int tid = threadIdx.x;
    __shared__ float cs[32], sn[32];
    if (tid < 32) {
        float fi = (float)tid;
        float freq   = exp2f(17.1946032f * (fi * (1.0f / 32.0f)));   // 150000^(i/32)
        float interp = 1.0f / (32.0f * freq);
        float extra  = 1.0f / freq;
        float ramp   = (fi - 8.0927802f) * (1.0f / (17.3980220f - 8.0927802f));
        float rc     = fminf(fmaxf(ramp, 0.0f), 1.0f);               // = 1 - mask
        float invf   = interp * rc + extra * (1.0f - rc);
        float ang    = (float)t * invf;
        cs[tid] = cosf(ang) * 1.3465736f;                            // * concentration
        sn[tid] = sinf(ang) * 1.3465736f;
    }
    __syncthreads();
    const u16* rowA = p1a + (long)t * QKVD;
    const u16* rowB = p1b + (long)t * QKVD;
    auto pair = [&](int col) -> float2 {
        u32 ua = *(const u32*)(rowA + col);
        u32 ub = *(const u32*)(rowB + col);
        float2 bb = *(const float2*)(b_qkv + col);
        return make_float2(bflo(ua) + bflo(ub) + bb.x, bfhi(ua) + bfhi(ub) + bb.y);
    };
    // Q: 64 heads x 32 pairs
    for (int p = tid; p < 2048; p += 256) {
        int hd2 = p >> 5, i = p & 31;
        float2 ab = pair(hd2 * 64 + 2 * i);
        float o1 = ab.x * cs[i] - ab.y * sn[i];
        float o2 = ab.y * cs[i] + ab.x * sn[i];
        *(u32*)(qr + (long)t * QD + hd2 * 64 + 2 * i) = (u32)f2bf(o1) | ((u32)f2bf(o2) << 16);
    }
    // K: 8 heads x 32 pairs == 256 threads; head-major layout [kv][t][64]
    {
        int kv = tid >> 5, i = tid & 31;
        float2 ab = pair(QD + kv * 64 + 2 * i);
        float o1 = ab.x * cs[i] - ab.y * sn[i];
        float o2 = ab.y * cs[i] + ab.x * sn[i];
        *(u32*)(kr + ((long)kv * TTOK + t) * HD + 2 * i) = (u32)f2bf(o1) | ((u32)f2bf(o2) << 16);
    }
    // V: 8 heads x 64 = 256 u32; head-major [kv][t][64]
    {
        int kv = tid >> 5, d2 = tid & 31;
        float2 ab = pair(QD + 512 + kv * 64 + 2 * d2);
        *(u32*)(vr + ((long)kv * TTOK + t) * HD + 2 * d2) = (u32)f2bf(ab.x) | ((u32)f2bf(ab.y) << 16);
    }
}

// ---------------- MFMA sliding-window attention with sink ----------------
__global__ __launch_bounds__(256, 2) void attn_kernel(const u16* __restrict__ qr,
                                                      const u16* __restrict__ kr,
                                                      const u16* __restrict__ vr,
                                                      const float* __restrict__ sinks,
                                                      u16* __restrict__ o) {
    const int t0  = blockIdx.x * 16;
    const int h   = blockIdx.y;
    const int qhg = blockIdx.z;
    const int tid = threadIdx.x;
    const int lane = tid & 63, wv = tid >> 6;
    __shared__ __align__(16) u16 ks[144][72];    // K rows [key][64+pad]
    __shared__ __align__(16) u16 Vt[64][168];    // V^T [d][key], cols 144..159 zero
    __shared__ __align__(16) u16 P [4][16][168]; // per-wave P [token][key], cols 144..159 zero
    const u16* kb = kr + (long)h * TTOK * HD;
    const u16* vb = vr + (long)h * TTOK * HD;

    // stage K rows (coalesced)
    #pragma unroll
    for (int i = 0; i < 5; ++i) {
        int idx = i * 256 + tid;
        if (idx < 144 * 8) {
            int rr = idx >> 3, c = idx & 7;
            int tk = t0 - 128 + rr;
            int tks = tk < 0 ? 0 : tk;          // clamped; masked later
            *(uint4*)&ks[rr][c * 8] = *(const uint4*)(kb + (long)tks * HD + c * 8);
        }
    }
    // stage V transposed: thread -> one key, 8 dims per pass
    #pragma unroll
    for (int c4 = 0; c4 < 8; ++c4) {
        if (tid < 144) {
            int tk = t0 - 128 + tid;
            int tks = tk < 0 ? 0 : tk;
            uint4 v4 = *(const uint4*)(vb + (long)tks * HD + c4 * 8);
            int d0 = c4 * 8;
            Vt[d0+0][tid] = (u16)(v4.x & 0xffff); Vt[d0+1][tid] = (u16)(v4.x >> 16);
            Vt[d0+2][tid] = (u16)(v4.y & 0xffff); Vt[d0+3][tid] = (u16)(v4.y >> 16);
            Vt[d0+4][tid] = (u16)(v4.z & 0xffff); Vt[d0+5][tid] = (u16)(v4.z >> 16);
            Vt[d0+6][tid] = (u16)(v4.w & 0xffff); Vt[d0+7][tid] = (u16)(v4.w >> 16);
        }
    }
    if (tid < 128) {
        *(uint4*)&Vt[tid >> 1][144 + (tid & 1) * 8] = uint4{0, 0, 0, 0};
    }
    if (lane < 32) {
        *(uint4*)&P[wv][lane >> 1][144 + (lane & 1) * 8] = uint4{0, 0, 0, 0};
    }
    __syncthreads();

    const int qh   = qhg * 4 + wv;
    const int head = h * QMULT + qh;
    const int fr = lane & 15, fk = (lane >> 4) * 8;
    const int cr = (lane >> 4) * 4;

    const u16* qrow = qr + (long)(t0 + fr) * QD + head * HD;
    bf16x8 qf0 = *(const bf16x8*)(qrow + fk);
    bf16x8 qf1 = *(const bf16x8*)(qrow + 32 + fk);

    const int kmin = 128 - t0;          // kk >= kmin <=> key token >= 0
    float lsum[4] = {0.f, 0.f, 0.f, 0.f};

    for (int nt = 0; nt < 9; ++nt) {
        bf16x8 b0 = *(const bf16x8*)&ks[nt * 16 + fr][fk];
        bf16x8 b1 = *(const bf16x8*)&ks[nt * 16 + fr][32 + fk];
        f32x4 s = f32x4{0.f, 0.f, 0.f, 0.f};
        s = __builtin_amdgcn_mfma_f32_16x16x32_bf16(qf0, b0, s, 0, 0, 0);
        s = __builtin_amdgcn_mfma_f32_16x16x32_bf16(qf1, b1, s, 0, 0, 0);
        const int kk = nt * 16 + fr;    // C-layout col = lane&15
        #pragma unroll
        for (int r = 0; r < 4; ++r) {
            int row = cr + r;           // token index within tile
            bool valid = (kk >= row) && (kk <= row + 128) && (kk >= kmin);
            float p = valid ? __expf(s[r] * 0.125f) : 0.0f;
            lsum[r] += p;
            P[wv][row][kk] = f2bf(p);
        }
    }

    f32x4 oacc[4];
    #pragma unroll
    for (int dt = 0; dt < 4; ++dt) oacc[dt] = f32x4{0.f, 0.f, 0.f, 0.f};
    #pragma unroll
    for (int k5 = 0; k5 < 5; ++k5) {
        const int k0 = k5 * 32;
        bf16x8 pa = *(const bf16x8*)&P[wv][fr][k0 + fk];
        #pragma unroll
        for (int dt = 0; dt < 4; ++dt) {
            bf16x8 vf = *(const bf16x8*)&Vt[dt * 16 + fr][k0 + fk];
            oacc[dt] = __builtin_amdgcn_mfma_f32_16x16x32_bf16(pa, vf, oacc[dt], 0, 0, 0);
        }
    }

    #pragma unroll
    for (int r = 0; r < 4; ++r) {
        float v = lsum[r];
        v += __shfl_xor(v, 1);
        v += __shfl_xor(v, 2);
        v += __shfl_xor(v, 4);
        v += __shfl_xor(v, 8);
        lsum[r] = v;
    }
    const float sk = exp2f(sinks[head]);
    float inv[4];
    #pragma unroll
    for (int r = 0; r < 4; ++r) inv[r] = 1.0f / (lsum[r] + sk);

    #pragma unroll
    for (int dt = 0; dt < 4; ++dt) {
        #pragma unroll
        for (int r = 0; r < 4; ++r) {
            o[(long)(t0 + cr + r) * QD + head * HD + dt * 16 + fr] = f2bf(oacc[dt][r] * inv[r]);
        }
    }
}

// ---------------- reduce GEMM2 partials + bias + residual -> out ----------------
__global__ __launch_bounds__(256) void reduce2_kernel(const u16* __restrict__ p2a,
                                                      const u16* __restrict__ p2b,
                                                      const float* __restrict__ x,
                                                      const float* __restrict__ b_out,
                                                      float* __restrict__ out) {
    const int row = blockIdx.y;
    const int c4 = blockIdx.x * 256 + threadIdx.x;   // float4 index within row
    if (c4 >= 720) return;
    const int col = c4 * 4;
    ushort4 ua = *(const ushort4*)(p2a + (long)row * NPAD + col);
    ushort4 ub = *(const ushort4*)(p2b + (long)row * NPAD + col);
    float4 xv = *(const float4*)(x + (long)row * HIDDEN + col);
    float4 bv = *(const float4*)(b_out + col);
    float4 o;
    o.x = xv.x + bv.x + __uint_as_float((u32)ua.x << 16) + __uint_as_float((u32)ub.x << 16);
    o.y = xv.y + bv.y + __uint_as_float((u32)ua.y << 16) + __uint_as_float((u32)ub.y << 16);
    o.z = xv.z + bv.z + __uint_as_float((u32)ua.z << 16) + __uint_as_float((u32)ub.z << 16);
    o.w = xv.w + bv.w + __uint_as_float((u32)ua.w << 16) + __uint_as_float((u32)ub.w << 16);
    *(float4*)(out + (long)row * HIDDEN + col) = o;
}

// ---------------- launcher ----------------
extern "C" void kernel_launch(void* const* d_in, const int* in_sizes, int n_in,
                              void* d_out, int out_size, void* d_ws, size_t ws_size,
                              hipStream_t stream) {
    const float* x      = (const float*)d_in[0];
    const float* nscale = (const float*)d_in[1];
    const float* w_qkv  = (const float*)d_in[2];
    const float* b_qkv  = (const float*)d_in[3];
    const float* sinks  = (const float*)d_in[4];
    const float* w_out  = (const float*)d_in[5];
    const float* b_out  = (const float*)d_in[6];
    float* out = (float*)d_out;

    char* ws = (char*)d_ws;
    size_t off = 0;
    auto alloc = [&](size_t bytes) { void* p = ws + off; off += (bytes + 255) & ~(size_t)255; return p; };
    u16* wqkv_bf = (u16*)alloc((size_t)QKVD * HIDDEN * 2);     // 29.5 MB
    u16* wout_bf = (u16*)alloc((size_t)NPAD * QD * 2);         // 24.1 MB
    u16* h       = (u16*)alloc((size_t)TTOK * HIDDEN * 2);     // 11.8 MB
    u16* p1      = (u16*)alloc((size_t)2 * TTOK * QKVD * 2);   // 42.0 MB (2 splits)
    u16* qrot    = (u16*)alloc((size_t)TTOK * QD * 2);         // 16.8 MB
    u16* krot    = (u16*)alloc((size_t)NKV * TTOK * HD * 2);   // 2.1 MB
    u16* vrot    = (u16*)alloc((size_t)NKV * TTOK * HD * 2);   // 2.1 MB
    // aliases (dead-after analysis):
    u16* attn = wqkv_bf;               // wqkv_bf dead after gemm1; attn [2048][4096] = 16.8 MB
    u16* p2   = p1;                    // p1 dead after rope; p2 = 2 x [2048][2944] = 24.1 MB

    prep_kernel<<<PREP_QKV_BLOCKS + PREP_WOUT_BLOCKS + PREP_RMS_BLOCKS, 256, 0, stream>>>(
        w_qkv, wqkv_bf, w_out, wout_bf, x, nscale, h);
    gemm_bt_part<<<dim3(QKVD / 128, TTOK / 128, 2), 256, 0, stream>>>(
        h, wqkv_bf, p1, QKVD, HIDDEN, HIDDEN / 2);
    rope_kernel<<<TTOK, 256, 0, stream>>>(
        p1, p1 + (size_t)TTOK * QKVD, b_qkv, qrot, krot, vrot);
    attn_kernel<<<dim3(TTOK / 16, NKV, 2), 256, 0, stream>>>(qrot, krot, vrot, sinks, attn);
    gemm_bt_part<<<dim3(NPAD / 128, TTOK / 128, 2), 256, 0, stream>>>(
        attn, wout_bf, p2, NPAD, QD, QD / 2);
    reduce2_kernel<<<dim3(3, TTOK), 256, 0, stream>>>(
        p2, p2 + (size_t)TTOK * NPAD, x, b_out, out);
}